// Round 6
// baseline (137.874 us; speedup 1.0000x reference)
//
#include <hip/hip_runtime.h>
#include <math.h>

#define NB 8
#define NC 512
#define NL1 1024
#define NL2 64
#define NLKV 1088
#define NENC 1024
#define EPSV 1e-5f
#define SCALE2 0.08838834764831845f          // 1/sqrt(128)
#define SCALE2Q 0.12752425f                  // SCALE2 * log2(e)
#define DEFER_THR 11.5415603f                // 8 nats in log2 units

typedef _Float16 half8 __attribute__((ext_vector_type(8)));
typedef _Float16 half4 __attribute__((ext_vector_type(4)));
typedef __fp16 fp16x2 __attribute__((ext_vector_type(2)));
typedef float f32x4 __attribute__((ext_vector_type(4)));
typedef float f32x16 __attribute__((ext_vector_type(16)));
typedef unsigned int uint32x2 __attribute__((ext_vector_type(2)));

__device__ __forceinline__ void gload16(const _Float16* g, _Float16* l) {
  __builtin_amdgcn_global_load_lds(
      (const __attribute__((address_space(1))) void*)g,
      (__attribute__((address_space(3))) void*)l, 16, 0, 0);
}

__device__ __forceinline__ unsigned int pkrtz(float a, float b) {
  union { fp16x2 hh; unsigned int uu; } cv;
  cv.hh = __builtin_amdgcn_cvt_pkrtz(a, b);
  return cv.uu;
}

__device__ __forceinline__ float fast_exp2(float x) {
  return __builtin_amdgcn_exp2f(x);
}

// ========== k_init: GN stats (x, obj_class) + all 4 weight converts ==========
__global__ __launch_bounds__(256) void k_init(
    const float* __restrict__ x, const float* __restrict__ obj,
    float* __restrict__ xm, float* __restrict__ xr,
    float* __restrict__ om, float* __restrict__ orr,
    const float* __restrict__ qkv_w, _Float16* __restrict__ w16qkv,
    const float* __restrict__ lp_w, _Float16* __restrict__ w16lp,
    const float* __restrict__ proj_w, _Float16* __restrict__ w16proj,
    const float* __restrict__ lc_w, _Float16* __restrict__ w16lc)
{
  int bid = blockIdx.x;
  if (bid < 512) {
    const float* p; float* meanp; float* rstdp; int n4, n, bg;
    if (bid < 256) {
      bg = bid;
      int b = bg >> 5, g = bg & 31;
      p = x + ((size_t)b * 512 + (size_t)g * 16) * 1024;
      n = 16 * 1024; meanp = xm; rstdp = xr;
    } else {
      bg = bid - 256;
      int b = bg >> 5, g = bg & 31;
      p = obj + ((size_t)b * 1024 + (size_t)g * 32) * 64;
      n = 32 * 64; meanp = om; rstdp = orr;
    }
    n4 = n >> 2;
    float s = 0.f, s2 = 0.f;
    for (int i = threadIdx.x; i < n4; i += 256) {
      float4 v = ((const float4*)p)[i];
      s += v.x + v.y + v.z + v.w;
      s2 += v.x * v.x + v.y * v.y + v.z * v.z + v.w * v.w;
    }
    #pragma unroll
    for (int o = 32; o > 0; o >>= 1) { s += __shfl_down(s, o); s2 += __shfl_down(s2, o); }
    __shared__ float rs[4], rq[4];
    int lane = threadIdx.x & 63, w = threadIdx.x >> 6;
    if (lane == 0) { rs[w] = s; rq[w] = s2; }
    __syncthreads();
    if (threadIdx.x == 0) {
      float S = rs[0] + rs[1] + rs[2] + rs[3];
      float Q = rq[0] + rq[1] + rq[2] + rq[3];
      float m = S / n;
      float v = Q / n - m * m;
      if (v < 0.f) v = 0.f;
      meanp[bg] = m;
      rstdp[bg] = rsqrtf(v + EPSV);
    }
  } else {
    int cb = bid - 512;
    const float* s; _Float16* d; int i4;
    if (cb < 768)        { s = qkv_w;  d = w16qkv;  i4 = cb * 256 + threadIdx.x; }
    else if (cb < 1280)  { s = lp_w;   d = w16lp;   i4 = (cb - 768) * 256 + threadIdx.x; }
    else if (cb < 1536)  { s = proj_w; d = w16proj; i4 = (cb - 1280) * 256 + threadIdx.x; }
    else                 { s = lc_w;   d = w16lc;   i4 = (cb - 1536) * 256 + threadIdx.x; }
    float4 v = *(const float4*)&s[(size_t)i4 * 4];
    half4 o; o.x = (_Float16)v.x; o.y = (_Float16)v.y; o.z = (_Float16)v.z; o.w = (_Float16)v.w;
    *(half4*)&d[(size_t)i4 * 4] = o;
  }
}

// ========== k_prep: gn_xT (1024) + ipbeT (2048) + lceobjT (256) ==========
__global__ __launch_bounds__(256) void k_prep(
    const float* __restrict__ x, const float* __restrict__ xm, const float* __restrict__ xr,
    const float* __restrict__ g_qkv, const float* __restrict__ b_qkv, _Float16* __restrict__ xT,
    const float* __restrict__ ipbe, _Float16* __restrict__ ipbeT,
    const float* __restrict__ xf_out, const float* __restrict__ obj_class,
    const float* __restrict__ obj_bbox,
    const float* __restrict__ om, const float* __restrict__ orr,
    const float* __restrict__ g_obj, const float* __restrict__ b_obj,
    _Float16* __restrict__ lceT, _Float16* __restrict__ objT)
{
  __shared__ _Float16 tile[64][72];
  const int bid = blockIdx.x;
  const int tl = threadIdx.x & 63;
  if (bid < 1024) {
    const int tt = bid & 15, ct = (bid >> 4) & 7, b = bid >> 7;
    const int c0 = ct * 64, t0 = tt * 64;
    const int cp = threadIdx.x >> 6;
    #pragma unroll
    for (int i = 0; i < 16; i++) {
      int c = c0 + i * 4 + cp;
      float v = x[((size_t)b * NC + c) * NL1 + t0 + tl];
      int g = c >> 4;
      float ga = g_qkv[c] * xr[b * 32 + g];
      float be = b_qkv[c] - xm[b * 32 + g] * ga;
      tile[tl][i * 4 + cp] = (_Float16)(v * ga + be);
    }
    __syncthreads();
    int tr = threadIdx.x >> 2, c16 = (threadIdx.x & 3) * 16;
    _Float16* dst = xT + ((size_t)b * 1024 + t0 + tr) * 512 + c0 + c16;
    *(half8*)dst = *(half8*)&tile[tr][c16];
    *(half8*)(dst + 8) = *(half8*)&tile[tr][c16 + 8];
  } else if (bid < 3072) {
    const int e2 = bid - 1024;
    const int tt = e2 & 15, et = (e2 >> 4) & 15, b = e2 >> 8;
    const int e0 = et * 64, t0 = tt * 64;
    const int ep = threadIdx.x >> 6;
    #pragma unroll
    for (int i = 0; i < 16; i++) {
      int e = e0 + i * 4 + ep;
      tile[tl][i * 4 + ep] = (_Float16)ipbe[((size_t)b * 1024 + e) * 1024 + t0 + tl];
    }
    __syncthreads();
    int tr = threadIdx.x >> 2, c16 = (threadIdx.x & 3) * 16;
    _Float16* d = ipbeT + ((size_t)b * 1024 + t0 + tr) * 1024 + e0 + c16;
    *(half8*)d = *(half8*)&tile[tr][c16];
    *(half8*)(d + 8) = *(half8*)&tile[tr][c16 + 8];
  } else {
    const int e2 = bid - 3072;
    const int et = e2 & 15, which = (e2 >> 4) & 1, b = e2 >> 5;
    const int e0 = et * 64;
    const int ep = threadIdx.x >> 6;
    if (which == 0) {
      #pragma unroll
      for (int i = 0; i < 16; i++) {
        int e = e0 + i * 4 + ep;
        size_t idx = ((size_t)b * 1024 + e) * 64 + tl;
        int g = e >> 5;
        float xn = (obj_class[idx] - om[b * 32 + g]) * orr[b * 32 + g] * g_obj[e] + b_obj[e];
        tile[tl][i * 4 + ep] = (_Float16)(0.5f * (xf_out[idx] + xn));
      }
    } else {
      #pragma unroll
      for (int i = 0; i < 16; i++) {
        int e = e0 + i * 4 + ep;
        tile[tl][i * 4 + ep] = (_Float16)obj_bbox[((size_t)b * 1024 + e) * 64 + tl];
      }
    }
    __syncthreads();
    int tr = threadIdx.x >> 2, c16 = (threadIdx.x & 3) * 16;
    _Float16* dst = (which == 0 ? lceT : objT) + ((size_t)b * 64 + tr) * 1024 + e0 + c16;
    *(half8*)dst = *(half8*)&tile[tr][c16];
    *(half8*)(dst + 8) = *(half8*)&tile[tr][c16 + 8];
  }
}

// =================== MFMA GEMM cores (2-phase double-buffered) ===================
#define MFMA_CORE(KTOT)                                                                  \
  f32x4 acc[4][4];                                                                       \
  _Pragma("unroll") for (int i_ = 0; i_ < 4; i_++)                                       \
      _Pragma("unroll") for (int j_ = 0; j_ < 4; j_++) acc[i_][j_] = (f32x4)0.f;         \
  {                                                                                      \
    const int rsub = lane >> 3, csrc = (lane & 7) ^ rsub;                                \
    const int NT_ = (KTOT) / 64;                                                         \
    _Pragma("unroll") for (int i = 0; i < 4; i++) {                                      \
      int seg = w * 4 + i;                                                               \
      int row = seg * 8 + rsub;                                                          \
      gload16(Abase + (size_t)(m0 + row) * (KTOT) + csrc * 8, ldsA + seg * 512);         \
      gload16(Bbase + (size_t)(n0 + row) * (KTOT) + csrc * 8, ldsB + seg * 512);         \
    }                                                                                    \
    __syncthreads();                                                                     \
    int cur_ = 0;                                                                        \
    for (int t_ = 0; t_ < NT_; t_++) {                                                   \
      if (t_ + 1 < NT_) {                                                                \
        _Float16* da_ = ldsA + ((cur_ ^ 1) << 13);                                       \
        _Float16* db_ = ldsB + ((cur_ ^ 1) << 13);                                       \
        int kt = (t_ + 1) * 64;                                                          \
        _Pragma("unroll") for (int i = 0; i < 4; i++) {                                  \
          int seg = w * 4 + i;                                                           \
          int row = seg * 8 + rsub;                                                      \
          gload16(Abase + (size_t)(m0 + row) * (KTOT) + kt + csrc * 8, da_ + seg * 512); \
          gload16(Bbase + (size_t)(n0 + row) * (KTOT) + kt + csrc * 8, db_ + seg * 512); \
        }                                                                                \
      }                                                                                  \
      const char* ra_ = (const char*)(ldsA + (cur_ << 13));                              \
      const char* rb_ = (const char*)(ldsB + (cur_ << 13));                              \
      _Pragma("unroll") for (int kk = 0; kk < 2; kk++) {                                 \
        half8 af[4], bf[4];                                                              \
        _Pragma("unroll") for (int mb = 0; mb < 4; mb++) {                               \
          int row = wm + mb * 16 + l15;                                                  \
          af[mb] = *(const half8*)(ra_ + row * 128 +                                     \
                                   ((kk * 64 + lg * 16) ^ ((row & 7) << 4)));            \
        }                                                                                \
        _Pragma("unroll") for (int nb = 0; nb < 4; nb++) {                               \
          int row = wn + nb * 16 + l15;                                                  \
          bf[nb] = *(const half8*)(rb_ + row * 128 +                                     \
                                   ((kk * 64 + lg * 16) ^ ((row & 7) << 4)));            \
        }                                                                                \
        _Pragma("unroll") for (int mb = 0; mb < 4; mb++)                                 \
            _Pragma("unroll") for (int nb = 0; nb < 4; nb++)                             \
                acc[mb][nb] = __builtin_amdgcn_mfma_f32_16x16x32_f16(af[mb], bf[nb],     \
                                                                    acc[mb][nb], 0, 0, 0);\
      }                                                                                  \
      __syncthreads();                                                                   \
      cur_ ^= 1;                                                                         \
    }                                                                                    \
  }

#define MFMA_CORE_N64(KTOT)                                                              \
  f32x4 acc[4][2];                                                                       \
  _Pragma("unroll") for (int i_ = 0; i_ < 4; i_++)                                       \
      _Pragma("unroll") for (int j_ = 0; j_ < 2; j_++) acc[i_][j_] = (f32x4)0.f;         \
  {                                                                                      \
    const int rsub = lane >> 3, csrc = (lane & 7) ^ rsub;                                \
    const int NT_ = (KTOT) / 64;                                                         \
    _Pragma("unroll") for (int i = 0; i < 4; i++) {                                      \
      int seg = w * 4 + i;                                                               \
      int row = seg * 8 + rsub;                                                          \
      gload16(Abase + (size_t)(m0 + row) * (KTOT) + csrc * 8, ldsA + seg * 512);         \
    }                                                                                    \
    _Pragma("unroll") for (int i = 0; i < 2; i++) {                                      \
      int seg = w * 2 + i;                                                               \
      int row = seg * 8 + rsub;                                                          \
      gload16(Bbase + (size_t)row * (KTOT) + csrc * 8, ldsB + seg * 512);                \
    }                                                                                    \
    __syncthreads();                                                                     \
    int cur_ = 0;                                                                        \
    for (int t_ = 0; t_ < NT_; t_++) {                                                   \
      if (t_ + 1 < NT_) {                                                                \
        _Float16* da_ = ldsA + ((cur_ ^ 1) << 13);                                       \
        _Float16* db_ = ldsB + ((cur_ ^ 1) << 12);                                       \
        int kt = (t_ + 1) * 64;                                                          \
        _Pragma("unroll") for (int i = 0; i < 4; i++) {                                  \
          int seg = w * 4 + i;                                                           \
          int row = seg * 8 + rsub;                                                      \
          gload16(Abase + (size_t)(m0 + row) * (KTOT) + kt + csrc * 8, da_ + seg * 512); \
        }                                                                                \
        _Pragma("unroll") for (int i = 0; i < 2; i++) {                                  \
          int seg = w * 2 + i;                                                           \
          int row = seg * 8 + rsub;                                                      \
          gload16(Bbase + (size_t)row * (KTOT) + kt + csrc * 8, db_ + seg * 512);        \
        }                                                                                \
      }                                                                                  \
      const char* ra_ = (const char*)(ldsA + (cur_ << 13));                              \
      const char* rb_ = (const char*)(ldsB + (cur_ << 12));                              \
      _Pragma("unroll") for (int kk = 0; kk < 2; kk++) {                                 \
        half8 af[4], bf[2];                                                              \
        _Pragma("unroll") for (int mb = 0; mb < 4; mb++) {                               \
          int row = wm + mb * 16 + l15;                                                  \
          af[mb] = *(const half8*)(ra_ + row * 128 +                                     \
                                   ((kk * 64 + lg * 16) ^ ((row & 7) << 4)));            \
        }                                                                                \
        _Pragma("unroll") for (int nb = 0; nb < 2; nb++) {                               \
          int row = wn + nb * 16 + l15;                                                  \
          bf[nb] = *(const half8*)(rb_ + row * 128 +                                     \
                                   ((kk * 64 + lg * 16) ^ ((row & 7) << 4)));            \
        }                                                                                \
        _Pragma("unroll") for (int mb = 0; mb < 4; mb++)                                 \
            _Pragma("unroll") for (int nb = 0; nb < 2; nb++)                             \
                acc[mb][nb] = __builtin_amdgcn_mfma_f32_16x16x32_f16(af[mb], bf[nb],     \
                                                                    acc[mb][nb], 0, 0, 0);\
      }                                                                                  \
      __syncthreads();                                                                   \
      cur_ ^= 1;                                                                         \
    }                                                                                    \
  }

// ====== k_mfma_big: ipp [0,256) + lc/lpe [256,352) + qkv [352,1120) ======
__global__ __launch_bounds__(256) void k_mfma_big(
    const _Float16* __restrict__ w16qkv, const float* __restrict__ qkv_b,
    const _Float16* __restrict__ xhatT,
    const _Float16* __restrict__ w16lp, const float* __restrict__ lp_b,
    const _Float16* __restrict__ ipbeT,
    const _Float16* __restrict__ w16lc, const float* __restrict__ lc_b,
    const _Float16* __restrict__ lceT, const _Float16* __restrict__ objT,
    const float* __restrict__ g_lpos, const float* __restrict__ b_lpos,
    _Float16* __restrict__ qT, _Float16* __restrict__ kT, _Float16* __restrict__ vT,
    _Float16* __restrict__ ipp16)
{
  __shared__ _Float16 smem[32768];   // 64KB: A dbuf [0,16384), B dbuf [16384,32768)
  const int bid0 = blockIdx.x;
  const int tid = threadIdx.x, lane = tid & 63, w = tid >> 6;
  const int l15 = lane & 15, lg = lane >> 4;

  if (bid0 < 256) {
    // ---- ipp: A = lp_w (512 x 1024), B = ipbeT, tile 128x128 ----
    const int nt = bid0 & 7, mt = (bid0 >> 3) & 3, b = bid0 >> 5;
    const int m0 = mt * 128, n0 = nt * 128;
    _Float16* ldsA = smem;
    _Float16* ldsB = smem + 16384;
    const _Float16* Abase = w16lp;
    const _Float16* Bbase = ipbeT + (size_t)b * 1024 * 1024;
    const int wm = (w >> 1) * 64, wn = (w & 1) * 64;
    MFMA_CORE(1024)
    #pragma unroll
    for (int mb = 0; mb < 4; mb++) {
      #pragma unroll
      for (int r = 0; r < 4; r++) {
        int m = m0 + wm + mb * 16 + lg * 4 + r;
        float bia = lp_b[m];
        #pragma unroll
        for (int nb = 0; nb < 4; nb++) {
          int t = n0 + wn + nb * 16 + l15;
          ipp16[((size_t)b * NC + m) * NL1 + t] = (_Float16)(acc[mb][nb][r] + bia);
        }
      }
    }
  } else if (bid0 < 352) {
    // ---- lc/lpe: tile 128x64, K=1024; lpe fuses GroupNorm ----
    const int local = bid0 - 256;
    const int mt = local % 12, b = local / 12;
    const bool islc = (mt < 8);
    const int m0 = (islc ? mt : mt - 8) * 128;
    _Float16* ldsA = smem;
    _Float16* ldsB = smem + 16384;
    float (*red_s)[4] = (float(*)[4])(smem + 24576);
    float (*red_q)[4] = (float(*)[4])(smem + 24608);
    const _Float16* Abase = islc ? w16lc : w16lp;
    const float* bias = islc ? lc_b : lp_b;
    const _Float16* Bbase = (islc ? lceT : objT) + (size_t)b * 64 * 1024;
    const int wm = (w >> 1) * 64, wn = (w & 1) * 32;
    MFMA_CORE_N64(1024)

    if (islc) {
      #pragma unroll
      for (int mb = 0; mb < 4; mb++) {
        #pragma unroll
        for (int r = 0; r < 4; r++) {
          int m = m0 + wm + mb * 16 + lg * 4 + r;
          float bia = bias[m];
          #pragma unroll
          for (int nb = 0; nb < 2; nb++) {
            int l = wn + nb * 16 + l15;
            float val = acc[mb][nb][r] + bia;
            if (m < 512) {
              int h = m >> 6, dc = m & 63;
              kT[(((size_t)b * 8 + h) * 1088 + 1024 + l) * 128 + dc] = (_Float16)val;
            } else {
              int mv = m - 512, h = mv >> 6, dc = mv & 63;
              vT[(((size_t)b * 8 + h) * 64 + dc) * 1088 + 1024 + l] = (_Float16)val;
            }
          }
        }
      }
    } else {
      float vals[4][2][4];
      float ps[4], pq[4];
      #pragma unroll
      for (int mb = 0; mb < 4; mb++) {
        ps[mb] = 0.f; pq[mb] = 0.f;
        #pragma unroll
        for (int r = 0; r < 4; r++) {
          int m = m0 + wm + mb * 16 + lg * 4 + r;
          float bia = bias[m];
          #pragma unroll
          for (int nb = 0; nb < 2; nb++) {
            float val = acc[mb][nb][r] + bia;
            vals[mb][nb][r] = val;
            ps[mb] += val; pq[mb] += val * val;
          }
        }
      }
      #pragma unroll
      for (int mb = 0; mb < 4; mb++) {
        #pragma unroll
        for (int o = 32; o > 0; o >>= 1) {
          ps[mb] += __shfl_xor(ps[mb], o);
          pq[mb] += __shfl_xor(pq[mb], o);
        }
      }
      if (lane == 0) {
        #pragma unroll
        for (int mb = 0; mb < 4; mb++) { red_s[w][mb] = ps[mb]; red_q[w][mb] = pq[mb]; }
      }
      __syncthreads();
      const int wbase = (wm >> 6) * 2;
      #pragma unroll
      for (int mb = 0; mb < 4; mb++) {
        float S = red_s[wbase][mb] + red_s[wbase + 1][mb];
        float Q = red_q[wbase][mb] + red_q[wbase + 1][mb];
        float mean = S * (1.f / 1024.f);
        float var = Q * (1.f / 1024.f) - mean * mean;
        if (var < 0.f) var = 0.f;
        float rstd = rsqrtf(var + EPSV);
        #pragma unroll
        for (int r = 0; r < 4; r++) {
          int c = m0 + wm + mb * 16 + lg * 4 + r;
          float ga = g_lpos[c] * rstd;
          float be = b_lpos[c] - mean * ga;
          int hh = c >> 6, dc = c & 63;
          #pragma unroll
          for (int nb = 0; nb < 2; nb++) {
            int l = wn + nb * 16 + l15;
            float xn = vals[mb][nb][r] * ga + be;
            kT[(((size_t)b * 8 + hh) * 1088 + 1024 + l) * 128 + 64 + dc] = (_Float16)xn;
          }
        }
      }
    }
  } else {
    // ---- qkv: A = qkv_w (1536 x 512), B = xhatT (1024 x 512), tile 128x128 ----
    const int bid = bid0 - 352;
    const int nt = bid & 7, tt = bid >> 3;
    const int mt = tt % 12, b = tt / 12;
    const int m0 = mt * 128, n0 = nt * 128;
    _Float16* ldsA = smem;
    _Float16* ldsB = smem + 16384;
    const _Float16* Abase = w16qkv;
    const _Float16* Bbase = xhatT + (size_t)b * 1024 * 512;
    const int wm = (w >> 1) * 64, wn = (w & 1) * 64;
    MFMA_CORE(512)

    char* tb = (char*)smem;
    if (m0 < 1024) {
      const bool isq = (m0 < 512);
      const float qs = isq ? SCALE2Q : 1.f;
      #pragma unroll
      for (int mb = 0; mb < 4; mb++) {
        #pragma unroll
        for (int r = 0; r < 4; r++) {
          int mcol = wm + mb * 16 + lg * 4 + r;
          float bia = qkv_b[m0 + mcol];
          #pragma unroll
          for (int nb = 0; nb < 4; nb++) {
            int trow = wn + nb * 16 + l15;
            float val = (acc[mb][nb][r] + bia) * qs;
            *(_Float16*)(tb + ((trow * 256 + mcol * 2) ^ ((trow & 7) << 4))) = (_Float16)val;
          }
        }
      }
      __syncthreads();
      #pragma unroll
      for (int it = 0; it < 8; it++) {
        int e = it * 256 + tid;
        int trow = e >> 4, seg = e & 15;
        half8 v = *(const half8*)(tb + ((trow * 256 + seg * 16) ^ ((trow & 7) << 4)));
        if (isq) {
          int mq = m0 + seg * 8, hh = mq >> 6, dc = mq & 63;
          *(half8*)(qT + (((size_t)b * 8 + hh) * 1024 + n0 + trow) * 128 + dc) = v;
        } else {
          int mk = m0 - 512 + seg * 8, hh = mk >> 6, dc = mk & 63;
          *(half8*)(kT + (((size_t)b * 8 + hh) * 1088 + n0 + trow) * 128 + dc) = v;
        }
      }
    } else {
      #pragma unroll
      for (int mb = 0; mb < 4; mb++) {
        #pragma unroll
        for (int r = 0; r < 4; r++) {
          int mrow = wm + mb * 16 + lg * 4 + r;
          float bia = qkv_b[m0 + mrow];
          #pragma unroll
          for (int nb = 0; nb < 4; nb++) {
            int tcol = wn + nb * 16 + l15;
            *(_Float16*)(tb + ((mrow * 256 + tcol * 2) ^ ((mrow & 7) << 4))) =
                (_Float16)(acc[mb][nb][r] + bia);
          }
        }
      }
      __syncthreads();
      #pragma unroll
      for (int it = 0; it < 8; it++) {
        int e = it * 256 + tid;
        int mrow = e >> 4, seg = e & 15;
        half8 v = *(const half8*)(tb + ((mrow * 256 + seg * 16) ^ ((mrow & 7) << 4)));
        int mv = m0 - 1024 + mrow, hh = mv >> 6, dc = mv & 63;
        *(half8*)(vT + (((size_t)b * 8 + hh) * 64 + dc) * 1088 + n0 + seg * 8) = v;
      }
    }
  }
}

// proj: A = proj_w f16 (512 x 512), B = attnT (1024 x 512); 128x64 tile, grid (16,4,8)
__global__ __launch_bounds__(256) void k_mfma_proj(
    const _Float16* __restrict__ Abase, const float* __restrict__ bias,
    const _Float16* __restrict__ Ball, const float* __restrict__ xin,
    float* __restrict__ out)
{
  __shared__ _Float16 smem[24576];   // 48KB: A dbuf [0,16384), B dbuf [16384,24576)
  _Float16* ldsA = smem;
  _Float16* ldsB = smem + 16384;
  const int b = blockIdx.z, mt = blockIdx.y, nt = blockIdx.x;
  const int m0 = mt * 128, n0 = nt * 64;
  const _Float16* Bbase = Ball + (size_t)b * 1024 * 512 + (size_t)n0 * 512;
  const int tid = threadIdx.x, lane = tid & 63, w = tid >> 6;
  const int l15 = lane & 15, lg = lane >> 4;
  const int wm = (w >> 1) * 64, wn = (w & 1) * 32;
  MFMA_CORE_N64(512)
  #pragma unroll
  for (int mb = 0; mb < 4; mb++) {
    #pragma unroll
    for (int r = 0; r < 4; r++) {
      int m = m0 + wm + mb * 16 + lg * 4 + r;
      float bia = bias[m];
      #pragma unroll
      for (int nb = 0; nb < 2; nb++) {
        int t = n0 + wn + nb * 16 + l15;
        size_t idx = ((size_t)b * NC + m) * NL1 + t;
        out[idx] = xin[idx] + acc[mb][nb][r] + bia;
      }
    }
  }
}

// ====== ipp GN stats + normalize + scatter fused (f16 input) ======
__global__ __launch_bounds__(256) void k_ipp_fuse(
    const _Float16* __restrict__ raw,
    const float* __restrict__ gm, const float* __restrict__ gb,
    _Float16* __restrict__ qT, _Float16* __restrict__ kT)
{
  const int g = blockIdx.x, b = blockIdx.y;
  const int tid = threadIdx.x;
  const _Float16* p = raw + ((size_t)b * 512 + (size_t)g * 16) * 1024;
  const int t0 = tid * 4;

  float4 v[16];
  float s = 0.f, s2 = 0.f;
  #pragma unroll
  for (int c = 0; c < 16; c++) {
    half4 hv = *(const half4*)&p[(size_t)c * 1024 + t0];
    v[c].x = (float)hv.x; v[c].y = (float)hv.y; v[c].z = (float)hv.z; v[c].w = (float)hv.w;
    s += v[c].x + v[c].y + v[c].z + v[c].w;
    s2 += v[c].x * v[c].x + v[c].y * v[c].y + v[c].z * v[c].z + v[c].w * v[c].w;
  }
  #pragma unroll
  for (int o = 32; o > 0; o >>= 1) { s += __shfl_down(s, o); s2 += __shfl_down(s2, o); }
  __shared__ float rs[4], rq[4], stat[2];
  int lane = tid & 63, w = tid >> 6;
  if (lane == 0) { rs[w] = s; rq[w] = s2; }
  __syncthreads();
  if (tid == 0) {
    float S = rs[0] + rs[1] + rs[2] + rs[3];
    float Q = rq[0] + rq[1] + rq[2] + rq[3];
    float mn = S / 16384.f;
    float var = Q / 16384.f - mn * mn;
    if (var < 0.f) var = 0.f;
    stat[0] = mn; stat[1] = rsqrtf(var + EPSV);
  }
  __syncthreads();
  const float mn = stat[0], rstd = stat[1];

  float ga[16], be[16];
  #pragma unroll
  for (int c = 0; c < 16; c++) {
    ga[c] = gm[g * 16 + c] * rstd;
    be[c] = gb[g * 16 + c] - mn * ga[c];
  }

  const size_t bh = (size_t)b * 8 + (g >> 2);
  const int dcb = (g & 3) * 16;
  #pragma unroll
  for (int j = 0; j < 4; j++) {
    const int t = t0 + j;
    half8 k0, k1, q0, q1;
    #pragma unroll
    for (int c = 0; c < 8; c++) {
      float4 vc = v[c];
      float e = (j == 0) ? vc.x : (j == 1) ? vc.y : (j == 2) ? vc.z : vc.w;
      float xn = e * ga[c] + be[c];
      k0[c] = (_Float16)xn;
      q0[c] = (_Float16)(SCALE2Q * xn);
    }
    #pragma unroll
    for (int c = 8; c < 16; c++) {
      float4 vc = v[c];
      float e = (j == 0) ? vc.x : (j == 1) ? vc.y : (j == 2) ? vc.z : vc.w;
      float xn = e * ga[c] + be[c];
      k1[c - 8] = (_Float16)xn;
      q1[c - 8] = (_Float16)(SCALE2Q * xn);
    }
    _Float16* qd = qT + (bh * 1024 + t) * 128 + 64 + dcb;
    _Float16* kd = kT + (bh * 1088 + t) * 128 + 64 + dcb;
    *(half8*)qd = q0; *(half8*)(qd + 8) = q1;
    *(half8*)kd = k0; *(half8*)(kd + 8) = k1;
  }
}

// ====================== fused attention (64 Q-rows/wave, 2 groups, depth-2 prefetch) ======================
// Round 6: each wave owns 64 Q rows (groups A = w*64+l31, B = +32). The 16 K + 8 V
// ds_read_b128 per iter now feed 2x the MFMAs (kf/vf shared across groups): LDS-read
// per FLOP halves, and QK has 4 independent 8-chains (A0,A1,B0,B1) -> 4-way MFMA ILP.
// Block = 4 waves = 256 rows; grid = 64 bh x 4 qt = 256 blocks (1/CU).
// K/V triple-buffered (%3), stage t+2 at iter t, counted vmcnt(6) (tail: 0).
__global__ __launch_bounds__(256, 1) void k_attn_mfma(
    const _Float16* __restrict__ qT, const _Float16* __restrict__ kT,
    const _Float16* __restrict__ vT, const int* __restrict__ mask,
    _Float16* __restrict__ attnT)
{
  const int bid = blockIdx.x;
  const int bh = bid >> 2;
  const int qt = bid & 3;
  const int b = bh >> 3, h = bh & 7;
  const int tid = threadIdx.x;
  const int lane = tid & 63;
  const int w = tid >> 6;
  const int l31 = lane & 31;
  const int hi = lane >> 5;

  __shared__ _Float16 KsB[3 * 64 * 128];   // 48KB, 3 buffers of 8192 halfs
  __shared__ _Float16 VtB[3 * 64 * 64];    // 24KB, 3 buffers of 4096 halfs

  const int qA = qt * 256 + w * 64 + l31;
  const int qB = qA + 32;

  half8 aqA[8], aqB[8];
  {
    const _Float16* qpA = qT + ((size_t)bh * 1024 + qA) * 128 + hi * 8;
    const _Float16* qpB = qT + ((size_t)bh * 1024 + qB) * 128 + hi * 8;
    #pragma unroll
    for (int kst = 0; kst < 8; kst++) {
      aqA[kst] = *(const half8*)(qpA + kst * 16);
      aqB[kst] = *(const half8*)(qpB + kst * 16);
    }
  }

  unsigned int mbits = 0;
  {
    const int* mp = mask + b * 64;
    #pragma unroll
    for (int sb = 0; sb < 2; sb++) {
      #pragma unroll
      for (int reg = 0; reg < 16; reg++) {
        int s = sb * 32 + (reg & 3) + 8 * (reg >> 2) + 4 * hi;
        if (mp[s]) mbits |= 1u << (sb * 16 + reg);
      }
    }
  }

  f32x16 OA0 = (f32x16)0.f, OA1 = (f32x16)0.f;
  f32x16 OB0 = (f32x16)0.f, OB1 = (f32x16)0.f;
  float mA = -INFINITY, lA = 0.f;
  float mB = -INFINITY, lB = 0.f;

  const int kxor = (l31 & 7) << 4;
  const int ksrow_off = lane >> 4;
  const int kcsrc_base = lane & 15;
  const int vdc_off = lane >> 3;
  const int vcsrc_base = lane & 7;

#define STAGE_KV(T, KD, VD)                                                          \
  {                                                                                  \
    const int s0_ = (T) * 64;                                                        \
    _Pragma("unroll") for (int r = 0; r < 4; r++) {                                  \
      int seg = r * 4 + w;                                                           \
      int srow = seg * 4 + ksrow_off;                                                \
      int csrc = kcsrc_base ^ (srow & 7);                                            \
      gload16(kT + ((size_t)bh * 1088 + s0_ + srow) * 128 + csrc * 8, (KD) + seg * 512); \
    }                                                                                \
    _Pragma("unroll") for (int r = 0; r < 2; r++) {                                  \
      int seg = r * 4 + w;                                                           \
      int dc = seg * 8 + vdc_off;                                                    \
      int csrc = vcsrc_base ^ (dc & 7);                                              \
      gload16(vT + ((size_t)bh * 64 + dc) * 1088 + s0_ + csrc * 8, (VD) + seg * 512);  \
    }                                                                                \
  }

// cross-half (lane^32) reduce via permlane32_swap builtin: OUT = OP(x[l], x[l^32])
#define XHALF_FMAX(OUTV, INV)                                                        \
  { unsigned int xi_ = __float_as_uint(INV);                                         \
    uint32x2 xr_ = __builtin_amdgcn_permlane32_swap(xi_, xi_, false, false);         \
    OUTV = fmaxf(__uint_as_float(xr_.x), __uint_as_float(xr_.y)); }
#define XHALF_ADD(OUTV, INV)                                                         \
  { unsigned int xi_ = __float_as_uint(INV);                                         \
    uint32x2 xr_ = __builtin_amdgcn_permlane32_swap(xi_, xi_, false, false);         \
    OUTV = __uint_as_float(xr_.x) + __uint_as_float(xr_.y); }

// online-softmax for one 32-row group held in (P0,P1), state (MRUN,LRUN), accum (O0,O1)
#define SOFTMAX_G(P0, P1, MRUN, LRUN, O0, O1)                                        \
  {                                                                                  \
    float mx;                                                                        \
    {                                                                                \
      float a0 = fmaxf(fmaxf(P0[0], P0[1]), P0[2]);                                  \
      float a1 = fmaxf(fmaxf(P0[3], P0[4]), P0[5]);                                  \
      float a2 = fmaxf(fmaxf(P0[6], P0[7]), P0[8]);                                  \
      float a3 = fmaxf(fmaxf(P0[9], P0[10]), P0[11]);                                \
      float a4 = fmaxf(fmaxf(P0[12], P0[13]), P0[14]);                               \
      float a5 = fmaxf(fmaxf(P0[15], P1[0]), P1[1]);                                 \
      float a6 = fmaxf(fmaxf(P1[2], P1[3]), P1[4]);                                  \
      float a7 = fmaxf(fmaxf(P1[5], P1[6]), P1[7]);                                  \
      float a8 = fmaxf(fmaxf(P1[8], P1[9]), P1[10]);                                 \
      float a9 = fmaxf(fmaxf(P1[11], P1[12]), P1[13]);                               \
      float aa = fmaxf(P1[14], P1[15]);                                              \
      float b0 = fmaxf(fmaxf(a0, a1), a2);                                           \
      float b1 = fmaxf(fmaxf(a3, a4), a5);                                           \
      float b2 = fmaxf(fmaxf(a6, a7), a8);                                           \
      float b3 = fmaxf(a9, aa);                                                      \
      mx = fmaxf(fmaxf(b0, b1), fmaxf(b2, b3));                                      \
    }                                                                                \
    XHALF_FMAX(mx, mx)                                                               \
    if (__all(mx <= MRUN + DEFER_THR)) {                                             \
      float sum = 0.f;                                                               \
      _Pragma("unroll") for (int i = 0; i < 16; i++) {                               \
        float p = fast_exp2(P0[i] - MRUN); P0[i] = p; sum += p; }                    \
      _Pragma("unroll") for (int i = 0; i < 16; i++) {                               \
        float p = fast_exp2(P1[i] - MRUN); P1[i] = p; sum += p; }                    \
      XHALF_ADD(sum, sum)                                                            \
      LRUN += sum;                                                                   \
    } else {                                                                         \
      float m_new = fmaxf(MRUN, mx);                                                 \
      float alpha = fast_exp2(MRUN - m_new);                                         \
      float sum = 0.f;                                                               \
      _Pragma("unroll") for (int i = 0; i < 16; i++) {                               \
        float p = fast_exp2(P0[i] - m_new); P0[i] = p; sum += p; }                   \
      _Pragma("unroll") for (int i = 0; i < 16; i++) {                               \
        float p = fast_exp2(P1[i] - m_new); P1[i] = p; sum += p; }                   \
      XHALF_ADD(sum, sum)                                                            \
      LRUN = LRUN * alpha + sum;                                                     \
      MRUN = m_new;                                                                  \
      _Pragma("unroll") for (int i = 0; i < 16; i++) { O0[i] *= alpha; O1[i] *= alpha; } \
    }                                                                                \
  }

// pack one group's P (post-exp) fragment for PV's kst = sb*2+k2 slot
#define PACK_PF(PFU, P0, P1)                                                         \
  { unsigned int pa0, pa1, pb0, pb1;                                                 \
    if (sb == 0) {                                                                   \
      pa0 = pkrtz(P0[8 * k2 + 0], P0[8 * k2 + 1]);                                   \
      pa1 = pkrtz(P0[8 * k2 + 2], P0[8 * k2 + 3]);                                   \
      pb0 = pkrtz(P0[8 * k2 + 4], P0[8 * k2 + 5]);                                   \
      pb1 = pkrtz(P0[8 * k2 + 6], P0[8 * k2 + 7]);                                   \
    } else {                                                                         \
      pa0 = pkrtz(P1[8 * k2 + 0], P1[8 * k2 + 1]);                                   \
      pa1 = pkrtz(P1[8 * k2 + 2], P1[8 * k2 + 3]);                                   \
      pb0 = pkrtz(P1[8 * k2 + 4], P1[8 * k2 + 5]);                                   \
      pb1 = pkrtz(P1[8 * k2 + 6], P1[8 * k2 + 7]);                                   \
    }                                                                                \
    uint32x2 r0_ = __builtin_amdgcn_permlane32_swap(pa0, pb0, false, false);         \
    uint32x2 r1_ = __builtin_amdgcn_permlane32_swap(pa1, pb1, false, false);         \
    PFU.u[0] = r0_.x; PFU.u[1] = r1_.x; PFU.u[2] = r0_.y; PFU.u[3] = r1_.y; }

  STAGE_KV(0, KsB, VtB)
  STAGE_KV(1, KsB + 8192, VtB + 4096)
  asm volatile("s_waitcnt vmcnt(6)" ::: "memory");
  __builtin_amdgcn_s_barrier();

  int bufR = 0;
  for (int t = 0; t <= 16; t++) {
    int bufS = bufR + 2; if (bufS >= 3) bufS -= 3;
    if (t <= 14) {
      _Float16* kd_ = KsB + bufS * 8192;
      _Float16* vd_ = VtB + bufS * 4096;
      STAGE_KV(t + 2, kd_, vd_)
    }
    const char* ksb_ = (const char*)(KsB + bufR * 8192);

    f32x16 scA0 = (f32x16)0.f, scA1 = (f32x16)0.f;
    f32x16 scB0 = (f32x16)0.f, scB1 = (f32x16)0.f;
    __builtin_amdgcn_s_setprio(1);
    #pragma unroll
    for (int kst = 0; kst < 8; kst++) {
      half8 kf0 = *(const half8*)(ksb_ + ((l31 * 256 + kst * 32 + hi * 16) ^ kxor));
      half8 kf1 = *(const half8*)(ksb_ + (((32 + l31) * 256 + kst * 32 + hi * 16) ^ kxor));
      scA0 = __builtin_amdgcn_mfma_f32_32x32x16_f16(kf0, aqA[kst], scA0, 0, 0, 0);
      scA1 = __builtin_amdgcn_mfma_f32_32x32x16_f16(kf1, aqA[kst], scA1, 0, 0, 0);
      scB0 = __builtin_amdgcn_mfma_f32_32x32x16_f16(kf0, aqB[kst], scB0, 0, 0, 0);
      scB1 = __builtin_amdgcn_mfma_f32_32x32x16_f16(kf1, aqB[kst], scB1, 0, 0, 0);
    }
    __builtin_amdgcn_s_setprio(0);

    if (t == 16) {
      #pragma unroll
      for (int i = 0; i < 16; i++) {
        if ((mbits >> i) & 1)        { scA0[i] = -INFINITY; scB0[i] = -INFINITY; }
        if ((mbits >> (16 + i)) & 1) { scA1[i] = -INFINITY; scB1[i] = -INFINITY; }
      }
    }

    SOFTMAX_G(scA0, scA1, mA, lA, OA0, OA1)
    SOFTMAX_G(scB0, scB1, mB, lB, OB0, OB1)

    const char* vtb_ = (const char*)(VtB + bufR * 4096);
    __builtin_amdgcn_s_setprio(1);
    #pragma unroll
    for (int sb = 0; sb < 2; sb++) {
      #pragma unroll
      for (int k2 = 0; k2 < 2; k2++) {
        const int kst = sb * 2 + k2;
        union { unsigned int u[4]; half8 hh; } pfA, pfB;
        PACK_PF(pfA, scA0, scA1)
        PACK_PF(pfB, scB0, scB1)
        half8 vf0 = *(const half8*)(vtb_ + ((l31 * 128 + kst * 32 + hi * 16) ^ kxor));
        half8 vf1 = *(const half8*)(vtb_ + (((32 + l31) * 128 + kst * 32 + hi * 16) ^ kxor));
        OA0 = __builtin_amdgcn_mfma_f32_32x32x16_f16(vf0, pfA.hh, OA0, 0, 0, 0);
        OA1 = __builtin_amdgcn_mfma_f32_32x32x16_f16(vf1, pfA.hh, OA1, 0, 0, 0);
        OB0 = __builtin_amdgcn_mfma_f32_32x32x16_f16(vf0, pfB.hh, OB0, 0, 0, 0);
        OB1 = __builtin_amdgcn_mfma_f32_32x32x16_f16(vf1, pfB.hh, OB1, 0, 0, 0);
      }
    }
    __builtin_amdgcn_s_setprio(0);

    if (t < 16) {
      if (t <= 14) asm volatile("s_waitcnt vmcnt(6)" ::: "memory");
      else         asm volatile("s_waitcnt vmcnt(0)" ::: "memory");
      __builtin_amdgcn_s_barrier();
    }
    bufR = bufR + 1; if (bufR >= 3) bufR -= 3;
  }

  float invA = 1.f / lA;
  float invB = 1.f / lB;
  _Float16* opA = attnT + ((size_t)b * 1024 + qA) * 512 + h * 64;
  _Float16* opB = attnT + ((size_t)b * 1024 + qB) * 512 + h * 64;
  #pragma unroll
  for (int i = 0; i < 16; i += 2) {
    int dc = (i & 3) + 8 * (i >> 2) + 4 * hi;
    *(unsigned int*)(opA + dc)      = pkrtz(OA0[i] * invA, OA0[i + 1] * invA);
    *(unsigned int*)(opA + 32 + dc) = pkrtz(OA1[i] * invA, OA1[i + 1] * invA);
    *(unsigned int*)(opB + dc)      = pkrtz(OB0[i] * invB, OB0[i + 1] * invB);
    *(unsigned int*)(opB + 32 + dc) = pkrtz(OB1[i] * invB, OB1[i + 1] * invB);
  }
}

// ============================ launcher ============================
extern "C" void kernel_launch(void* const* d_in, const int* in_sizes, int n_in,
                              void* d_out, int out_size, void* d_ws, size_t ws_size,
                              hipStream_t stream) {
  const float* x         = (const float*)d_in[0];
  const float* xf_out    = (const float*)d_in[1];
  const float* obj_class = (const float*)d_in[2];
  const float* obj_bbox  = (const float*)d_in[3];
  const float* ipbe      = (const float*)d_in[4];
  const int*   mask      = (const int*)d_in[5];
  const float* qkv_w     = (const float*)d_in[6];
  const float* qkv_b     = (const float*)d_in[7];
  const float* g_qkv     = (const float*)d_in[8];
  const float* b_qkv     = (const float*)d_in[9];
  const float* lc_w      = (const float*)d_in[10];
  const float* lc_b      = (const float*)d_in[11];
  const float* lp_w      = (const float*)d_in[12];
  const float* lp_b      = (const float*)d_in[13];
  const float* g_obj     = (const float*)d_in[14];
  const float* b_obj     = (const float*)d_in[15];
  const float* g_lpos    = (const float*)d_in[16];
  const float* b_lpos    = (const float*)d_in[17];
  const float* g_ipos    = (const float*)d_in[18];
  const float* b_ipos    = (const float*)d_in[19];
  const float* proj_w    = (const float*)d_in[20];
  const float* proj_b    = (const float*)d_in[21];
  float* out = (float*)d_out;

  _Float16* f16b = (_Float16*)d_ws;
  _Float16* qT      = f16b;                      // 8,388,608
  _Float16* kT      = qT + 8388608;              // 8,912,896
  _Float16* vT      = kT + 8912896;              // 4,456,448
  _Float16* xhatT   = vT + 4456448;              // 4,194,304
  _Float16* ipbeT   = xhatT + 4194304;           // 8,388,608
  _Float16* attnT   = ipbeT + 8388608;           // 4,194,304
  _Float16* w16qkv  = attnT + 4194304;           //   786,432
  _Float16* w16lp   = w16qkv + 786432;           //   524,288
  _Float16* w16proj = w16lp + 524288;            //   262,144
  _Float16* w16lc   = w16proj + 262144;          // 1,048,576
  _Float16* lceT    = w16lc + 1048576;           //   524,288
  _Float16* objT    = lceT + 524288;             //   524,288
  _Float16* ipp16   = objT + 524288;             // 4,194,304
  float* st = (float*)(ipp16 + 4194304);
  float* xm = st, * xr = st + 256, * om = st + 512, * orr = st + 768;

  dim3 blk(256);
  k_init<<<dim3(3072), blk, 0, stream>>>(x, obj_class, xm, xr, om, orr,
                                         qkv_w, w16qkv, lp_w, w16lp, proj_w, w16proj, lc_w, w16lc);
  k_prep<<<dim3(3328), blk, 0, stream>>>(x, xm, xr, g_qkv, b_qkv, xhatT,
                                         ipbe, ipbeT,
                                         xf_out, obj_class, obj_bbox, om, orr, g_obj, b_obj,
                                         lceT, objT);
  k_mfma_big<<<dim3(1120), blk, 0, stream>>>(w16qkv, qkv_b, xhatT,
                                             w16lp, lp_b, ipbeT,
                                             w16lc, lc_b, lceT, objT,
                                             g_lpos, b_lpos,
                                             qT, kT, vT, ipp16);
  k_ipp_fuse<<<dim3(32, 8), blk, 0, stream>>>(ipp16, g_ipos, b_ipos, qT, kT);
  k_attn_mfma<<<dim3(256), blk, 0, stream>>>(qT, kT, vT, mask, attnT);
  k_mfma_proj<<<dim3(16, 4, 8), blk, 0, stream>>>(w16proj, proj_b, attnT, x, out);
}

// Round 7
// 125.673 us; speedup vs baseline: 1.0971x; 1.0971x over previous
//
#include <hip/hip_runtime.h>
#include <math.h>

#define NB 8
#define NC 512
#define NL1 1024
#define NL2 64
#define NLKV 1088
#define NENC 1024
#define EPSV 1e-5f
#define SCALE2 0.08838834764831845f          // 1/sqrt(128)
#define SCALE2Q 0.12752425f                  // SCALE2 * log2(e)
#define DEFER_THR 11.5415603f                // 8 nats in log2 units

typedef _Float16 half8 __attribute__((ext_vector_type(8)));
typedef _Float16 half4 __attribute__((ext_vector_type(4)));
typedef __fp16 fp16x2 __attribute__((ext_vector_type(2)));
typedef float f32x4 __attribute__((ext_vector_type(4)));
typedef float f32x16 __attribute__((ext_vector_type(16)));
typedef unsigned int uint32x2 __attribute__((ext_vector_type(2)));

__device__ __forceinline__ void gload16(const _Float16* g, _Float16* l) {
  __builtin_amdgcn_global_load_lds(
      (const __attribute__((address_space(1))) void*)g,
      (__attribute__((address_space(3))) void*)l, 16, 0, 0);
}

__device__ __forceinline__ unsigned int pkrtz(float a, float b) {
  union { fp16x2 hh; unsigned int uu; } cv;
  cv.hh = __builtin_amdgcn_cvt_pkrtz(a, b);
  return cv.uu;
}

__device__ __forceinline__ float fast_exp2(float x) {
  return __builtin_amdgcn_exp2f(x);
}

// ========== k_init: GN stats (x, obj_class) + all 4 weight converts ==========
__global__ __launch_bounds__(256) void k_init(
    const float* __restrict__ x, const float* __restrict__ obj,
    float* __restrict__ xm, float* __restrict__ xr,
    float* __restrict__ om, float* __restrict__ orr,
    const float* __restrict__ qkv_w, _Float16* __restrict__ w16qkv,
    const float* __restrict__ lp_w, _Float16* __restrict__ w16lp,
    const float* __restrict__ proj_w, _Float16* __restrict__ w16proj,
    const float* __restrict__ lc_w, _Float16* __restrict__ w16lc)
{
  int bid = blockIdx.x;
  if (bid < 512) {
    const float* p; float* meanp; float* rstdp; int n4, n, bg;
    if (bid < 256) {
      bg = bid;
      int b = bg >> 5, g = bg & 31;
      p = x + ((size_t)b * 512 + (size_t)g * 16) * 1024;
      n = 16 * 1024; meanp = xm; rstdp = xr;
    } else {
      bg = bid - 256;
      int b = bg >> 5, g = bg & 31;
      p = obj + ((size_t)b * 1024 + (size_t)g * 32) * 64;
      n = 32 * 64; meanp = om; rstdp = orr;
    }
    n4 = n >> 2;
    float s = 0.f, s2 = 0.f;
    for (int i = threadIdx.x; i < n4; i += 256) {
      float4 v = ((const float4*)p)[i];
      s += v.x + v.y + v.z + v.w;
      s2 += v.x * v.x + v.y * v.y + v.z * v.z + v.w * v.w;
    }
    #pragma unroll
    for (int o = 32; o > 0; o >>= 1) { s += __shfl_down(s, o); s2 += __shfl_down(s2, o); }
    __shared__ float rs[4], rq[4];
    int lane = threadIdx.x & 63, w = threadIdx.x >> 6;
    if (lane == 0) { rs[w] = s; rq[w] = s2; }
    __syncthreads();
    if (threadIdx.x == 0) {
      float S = rs[0] + rs[1] + rs[2] + rs[3];
      float Q = rq[0] + rq[1] + rq[2] + rq[3];
      float m = S / n;
      float v = Q / n - m * m;
      if (v < 0.f) v = 0.f;
      meanp[bg] = m;
      rstdp[bg] = rsqrtf(v + EPSV);
    }
  } else {
    int cb = bid - 512;
    const float* s; _Float16* d; int i4;
    if (cb < 768)        { s = qkv_w;  d = w16qkv;  i4 = cb * 256 + threadIdx.x; }
    else if (cb < 1280)  { s = lp_w;   d = w16lp;   i4 = (cb - 768) * 256 + threadIdx.x; }
    else if (cb < 1536)  { s = proj_w; d = w16proj; i4 = (cb - 1280) * 256 + threadIdx.x; }
    else                 { s = lc_w;   d = w16lc;   i4 = (cb - 1536) * 256 + threadIdx.x; }
    float4 v = *(const float4*)&s[(size_t)i4 * 4];
    half4 o; o.x = (_Float16)v.x; o.y = (_Float16)v.y; o.z = (_Float16)v.z; o.w = (_Float16)v.w;
    *(half4*)&d[(size_t)i4 * 4] = o;
  }
}

// ========== k_prep: gn_xT (1024) + ipbeT (2048) + lceobjT (256) ==========
__global__ __launch_bounds__(256) void k_prep(
    const float* __restrict__ x, const float* __restrict__ xm, const float* __restrict__ xr,
    const float* __restrict__ g_qkv, const float* __restrict__ b_qkv, _Float16* __restrict__ xT,
    const float* __restrict__ ipbe, _Float16* __restrict__ ipbeT,
    const float* __restrict__ xf_out, const float* __restrict__ obj_class,
    const float* __restrict__ obj_bbox,
    const float* __restrict__ om, const float* __restrict__ orr,
    const float* __restrict__ g_obj, const float* __restrict__ b_obj,
    _Float16* __restrict__ lceT, _Float16* __restrict__ objT)
{
  __shared__ _Float16 tile[64][72];
  const int bid = blockIdx.x;
  const int tl = threadIdx.x & 63;
  if (bid < 1024) {
    const int tt = bid & 15, ct = (bid >> 4) & 7, b = bid >> 7;
    const int c0 = ct * 64, t0 = tt * 64;
    const int cp = threadIdx.x >> 6;
    #pragma unroll
    for (int i = 0; i < 16; i++) {
      int c = c0 + i * 4 + cp;
      float v = x[((size_t)b * NC + c) * NL1 + t0 + tl];
      int g = c >> 4;
      float ga = g_qkv[c] * xr[b * 32 + g];
      float be = b_qkv[c] - xm[b * 32 + g] * ga;
      tile[tl][i * 4 + cp] = (_Float16)(v * ga + be);
    }
    __syncthreads();
    int tr = threadIdx.x >> 2, c16 = (threadIdx.x & 3) * 16;
    _Float16* dst = xT + ((size_t)b * 1024 + t0 + tr) * 512 + c0 + c16;
    *(half8*)dst = *(half8*)&tile[tr][c16];
    *(half8*)(dst + 8) = *(half8*)&tile[tr][c16 + 8];
  } else if (bid < 3072) {
    const int e2 = bid - 1024;
    const int tt = e2 & 15, et = (e2 >> 4) & 15, b = e2 >> 8;
    const int e0 = et * 64, t0 = tt * 64;
    const int ep = threadIdx.x >> 6;
    #pragma unroll
    for (int i = 0; i < 16; i++) {
      int e = e0 + i * 4 + ep;
      tile[tl][i * 4 + ep] = (_Float16)ipbe[((size_t)b * 1024 + e) * 1024 + t0 + tl];
    }
    __syncthreads();
    int tr = threadIdx.x >> 2, c16 = (threadIdx.x & 3) * 16;
    _Float16* d = ipbeT + ((size_t)b * 1024 + t0 + tr) * 1024 + e0 + c16;
    *(half8*)d = *(half8*)&tile[tr][c16];
    *(half8*)(d + 8) = *(half8*)&tile[tr][c16 + 8];
  } else {
    const int e2 = bid - 3072;
    const int et = e2 & 15, which = (e2 >> 4) & 1, b = e2 >> 5;
    const int e0 = et * 64;
    const int ep = threadIdx.x >> 6;
    if (which == 0) {
      #pragma unroll
      for (int i = 0; i < 16; i++) {
        int e = e0 + i * 4 + ep;
        size_t idx = ((size_t)b * 1024 + e) * 64 + tl;
        int g = e >> 5;
        float xn = (obj_class[idx] - om[b * 32 + g]) * orr[b * 32 + g] * g_obj[e] + b_obj[e];
        tile[tl][i * 4 + ep] = (_Float16)(0.5f * (xf_out[idx] + xn));
      }
    } else {
      #pragma unroll
      for (int i = 0; i < 16; i++) {
        int e = e0 + i * 4 + ep;
        tile[tl][i * 4 + ep] = (_Float16)obj_bbox[((size_t)b * 1024 + e) * 64 + tl];
      }
    }
    __syncthreads();
    int tr = threadIdx.x >> 2, c16 = (threadIdx.x & 3) * 16;
    _Float16* dst = (which == 0 ? lceT : objT) + ((size_t)b * 64 + tr) * 1024 + e0 + c16;
    *(half8*)dst = *(half8*)&tile[tr][c16];
    *(half8*)(dst + 8) = *(half8*)&tile[tr][c16 + 8];
  }
}

// =================== MFMA GEMM cores (2-phase double-buffered) ===================
#define MFMA_CORE(KTOT)                                                                  \
  f32x4 acc[4][4];                                                                       \
  _Pragma("unroll") for (int i_ = 0; i_ < 4; i_++)                                       \
      _Pragma("unroll") for (int j_ = 0; j_ < 4; j_++) acc[i_][j_] = (f32x4)0.f;         \
  {                                                                                      \
    const int rsub = lane >> 3, csrc = (lane & 7) ^ rsub;                                \
    const int NT_ = (KTOT) / 64;                                                         \
    _Pragma("unroll") for (int i = 0; i < 4; i++) {                                      \
      int seg = w * 4 + i;                                                               \
      int row = seg * 8 + rsub;                                                          \
      gload16(Abase + (size_t)(m0 + row) * (KTOT) + csrc * 8, ldsA + seg * 512);         \
      gload16(Bbase + (size_t)(n0 + row) * (KTOT) + csrc * 8, ldsB + seg * 512);         \
    }                                                                                    \
    __syncthreads();                                                                     \
    int cur_ = 0;                                                                        \
    for (int t_ = 0; t_ < NT_; t_++) {                                                   \
      if (t_ + 1 < NT_) {                                                                \
        _Float16* da_ = ldsA + ((cur_ ^ 1) << 13);                                       \
        _Float16* db_ = ldsB + ((cur_ ^ 1) << 13);                                       \
        int kt = (t_ + 1) * 64;                                                          \
        _Pragma("unroll") for (int i = 0; i < 4; i++) {                                  \
          int seg = w * 4 + i;                                                           \
          int row = seg * 8 + rsub;                                                      \
          gload16(Abase + (size_t)(m0 + row) * (KTOT) + kt + csrc * 8, da_ + seg * 512); \
          gload16(Bbase + (size_t)(n0 + row) * (KTOT) + kt + csrc * 8, db_ + seg * 512); \
        }                                                                                \
      }                                                                                  \
      const char* ra_ = (const char*)(ldsA + (cur_ << 13));                              \
      const char* rb_ = (const char*)(ldsB + (cur_ << 13));                              \
      _Pragma("unroll") for (int kk = 0; kk < 2; kk++) {                                 \
        half8 af[4], bf[4];                                                              \
        _Pragma("unroll") for (int mb = 0; mb < 4; mb++) {                               \
          int row = wm + mb * 16 + l15;                                                  \
          af[mb] = *(const half8*)(ra_ + row * 128 +                                     \
                                   ((kk * 64 + lg * 16) ^ ((row & 7) << 4)));            \
        }                                                                                \
        _Pragma("unroll") for (int nb = 0; nb < 4; nb++) {                               \
          int row = wn + nb * 16 + l15;                                                  \
          bf[nb] = *(const half8*)(rb_ + row * 128 +                                     \
                                   ((kk * 64 + lg * 16) ^ ((row & 7) << 4)));            \
        }                                                                                \
        _Pragma("unroll") for (int mb = 0; mb < 4; mb++)                                 \
            _Pragma("unroll") for (int nb = 0; nb < 4; nb++)                             \
                acc[mb][nb] = __builtin_amdgcn_mfma_f32_16x16x32_f16(af[mb], bf[nb],     \
                                                                    acc[mb][nb], 0, 0, 0);\
      }                                                                                  \
      __syncthreads();                                                                   \
      cur_ ^= 1;                                                                         \
    }                                                                                    \
  }

#define MFMA_CORE_N64(KTOT)                                                              \
  f32x4 acc[4][2];                                                                       \
  _Pragma("unroll") for (int i_ = 0; i_ < 4; i_++)                                       \
      _Pragma("unroll") for (int j_ = 0; j_ < 2; j_++) acc[i_][j_] = (f32x4)0.f;         \
  {                                                                                      \
    const int rsub = lane >> 3, csrc = (lane & 7) ^ rsub;                                \
    const int NT_ = (KTOT) / 64;                                                         \
    _Pragma("unroll") for (int i = 0; i < 4; i++) {                                      \
      int seg = w * 4 + i;                                                               \
      int row = seg * 8 + rsub;                                                          \
      gload16(Abase + (size_t)(m0 + row) * (KTOT) + csrc * 8, ldsA + seg * 512);         \
    }                                                                                    \
    _Pragma("unroll") for (int i = 0; i < 2; i++) {                                      \
      int seg = w * 2 + i;                                                               \
      int row = seg * 8 + rsub;                                                          \
      gload16(Bbase + (size_t)row * (KTOT) + csrc * 8, ldsB + seg * 512);                \
    }                                                                                    \
    __syncthreads();                                                                     \
    int cur_ = 0;                                                                        \
    for (int t_ = 0; t_ < NT_; t_++) {                                                   \
      if (t_ + 1 < NT_) {                                                                \
        _Float16* da_ = ldsA + ((cur_ ^ 1) << 13);                                       \
        _Float16* db_ = ldsB + ((cur_ ^ 1) << 12);                                       \
        int kt = (t_ + 1) * 64;                                                          \
        _Pragma("unroll") for (int i = 0; i < 4; i++) {                                  \
          int seg = w * 4 + i;                                                           \
          int row = seg * 8 + rsub;                                                      \
          gload16(Abase + (size_t)(m0 + row) * (KTOT) + kt + csrc * 8, da_ + seg * 512); \
        }                                                                                \
        _Pragma("unroll") for (int i = 0; i < 2; i++) {                                  \
          int seg = w * 2 + i;                                                           \
          int row = seg * 8 + rsub;                                                      \
          gload16(Bbase + (size_t)row * (KTOT) + kt + csrc * 8, db_ + seg * 512);        \
        }                                                                                \
      }                                                                                  \
      const char* ra_ = (const char*)(ldsA + (cur_ << 13));                              \
      const char* rb_ = (const char*)(ldsB + (cur_ << 12));                              \
      _Pragma("unroll") for (int kk = 0; kk < 2; kk++) {                                 \
        half8 af[4], bf[2];                                                              \
        _Pragma("unroll") for (int mb = 0; mb < 4; mb++) {                               \
          int row = wm + mb * 16 + l15;                                                  \
          af[mb] = *(const half8*)(ra_ + row * 128 +                                     \
                                   ((kk * 64 + lg * 16) ^ ((row & 7) << 4)));            \
        }                                                                                \
        _Pragma("unroll") for (int nb = 0; nb < 2; nb++) {                               \
          int row = wn + nb * 16 + l15;                                                  \
          bf[nb] = *(const half8*)(rb_ + row * 128 +                                     \
                                   ((kk * 64 + lg * 16) ^ ((row & 7) << 4)));            \
        }                                                                                \
        _Pragma("unroll") for (int mb = 0; mb < 4; mb++)                                 \
            _Pragma("unroll") for (int nb = 0; nb < 2; nb++)                             \
                acc[mb][nb] = __builtin_amdgcn_mfma_f32_16x16x32_f16(af[mb], bf[nb],     \
                                                                    acc[mb][nb], 0, 0, 0);\
      }                                                                                  \
      __syncthreads();                                                                   \
      cur_ ^= 1;                                                                         \
    }                                                                                    \
  }

// ====== k_mfma_big: ipp [0,256) + lc/lpe [256,352) + qkv [352,1120) ======
__global__ __launch_bounds__(256) void k_mfma_big(
    const _Float16* __restrict__ w16qkv, const float* __restrict__ qkv_b,
    const _Float16* __restrict__ xhatT,
    const _Float16* __restrict__ w16lp, const float* __restrict__ lp_b,
    const _Float16* __restrict__ ipbeT,
    const _Float16* __restrict__ w16lc, const float* __restrict__ lc_b,
    const _Float16* __restrict__ lceT, const _Float16* __restrict__ objT,
    const float* __restrict__ g_lpos, const float* __restrict__ b_lpos,
    _Float16* __restrict__ qT, _Float16* __restrict__ kT, _Float16* __restrict__ vT,
    _Float16* __restrict__ ipp16)
{
  __shared__ _Float16 smem[32768];   // 64KB: A dbuf [0,16384), B dbuf [16384,32768)
  const int bid0 = blockIdx.x;
  const int tid = threadIdx.x, lane = tid & 63, w = tid >> 6;
  const int l15 = lane & 15, lg = lane >> 4;

  if (bid0 < 256) {
    // ---- ipp: A = lp_w (512 x 1024), B = ipbeT, tile 128x128 ----
    const int nt = bid0 & 7, mt = (bid0 >> 3) & 3, b = bid0 >> 5;
    const int m0 = mt * 128, n0 = nt * 128;
    _Float16* ldsA = smem;
    _Float16* ldsB = smem + 16384;
    const _Float16* Abase = w16lp;
    const _Float16* Bbase = ipbeT + (size_t)b * 1024 * 1024;
    const int wm = (w >> 1) * 64, wn = (w & 1) * 64;
    MFMA_CORE(1024)
    #pragma unroll
    for (int mb = 0; mb < 4; mb++) {
      #pragma unroll
      for (int r = 0; r < 4; r++) {
        int m = m0 + wm + mb * 16 + lg * 4 + r;
        float bia = lp_b[m];
        #pragma unroll
        for (int nb = 0; nb < 4; nb++) {
          int t = n0 + wn + nb * 16 + l15;
          ipp16[((size_t)b * NC + m) * NL1 + t] = (_Float16)(acc[mb][nb][r] + bia);
        }
      }
    }
  } else if (bid0 < 352) {
    // ---- lc/lpe: tile 128x64, K=1024; lpe fuses GroupNorm ----
    const int local = bid0 - 256;
    const int mt = local % 12, b = local / 12;
    const bool islc = (mt < 8);
    const int m0 = (islc ? mt : mt - 8) * 128;
    _Float16* ldsA = smem;
    _Float16* ldsB = smem + 16384;
    float (*red_s)[4] = (float(*)[4])(smem + 24576);
    float (*red_q)[4] = (float(*)[4])(smem + 24608);
    const _Float16* Abase = islc ? w16lc : w16lp;
    const float* bias = islc ? lc_b : lp_b;
    const _Float16* Bbase = (islc ? lceT : objT) + (size_t)b * 64 * 1024;
    const int wm = (w >> 1) * 64, wn = (w & 1) * 32;
    MFMA_CORE_N64(1024)

    if (islc) {
      #pragma unroll
      for (int mb = 0; mb < 4; mb++) {
        #pragma unroll
        for (int r = 0; r < 4; r++) {
          int m = m0 + wm + mb * 16 + lg * 4 + r;
          float bia = bias[m];
          #pragma unroll
          for (int nb = 0; nb < 2; nb++) {
            int l = wn + nb * 16 + l15;
            float val = acc[mb][nb][r] + bia;
            if (m < 512) {
              int h = m >> 6, dc = m & 63;
              kT[(((size_t)b * 8 + h) * 1088 + 1024 + l) * 128 + dc] = (_Float16)val;
            } else {
              int mv = m - 512, h = mv >> 6, dc = mv & 63;
              vT[(((size_t)b * 8 + h) * 64 + dc) * 1088 + 1024 + l] = (_Float16)val;
            }
          }
        }
      }
    } else {
      float vals[4][2][4];
      float ps[4], pq[4];
      #pragma unroll
      for (int mb = 0; mb < 4; mb++) {
        ps[mb] = 0.f; pq[mb] = 0.f;
        #pragma unroll
        for (int r = 0; r < 4; r++) {
          int m = m0 + wm + mb * 16 + lg * 4 + r;
          float bia = bias[m];
          #pragma unroll
          for (int nb = 0; nb < 2; nb++) {
            float val = acc[mb][nb][r] + bia;
            vals[mb][nb][r] = val;
            ps[mb] += val; pq[mb] += val * val;
          }
        }
      }
      #pragma unroll
      for (int mb = 0; mb < 4; mb++) {
        #pragma unroll
        for (int o = 32; o > 0; o >>= 1) {
          ps[mb] += __shfl_xor(ps[mb], o);
          pq[mb] += __shfl_xor(pq[mb], o);
        }
      }
      if (lane == 0) {
        #pragma unroll
        for (int mb = 0; mb < 4; mb++) { red_s[w][mb] = ps[mb]; red_q[w][mb] = pq[mb]; }
      }
      __syncthreads();
      const int wbase = (wm >> 6) * 2;
      #pragma unroll
      for (int mb = 0; mb < 4; mb++) {
        float S = red_s[wbase][mb] + red_s[wbase + 1][mb];
        float Q = red_q[wbase][mb] + red_q[wbase + 1][mb];
        float mean = S * (1.f / 1024.f);
        float var = Q * (1.f / 1024.f) - mean * mean;
        if (var < 0.f) var = 0.f;
        float rstd = rsqrtf(var + EPSV);
        #pragma unroll
        for (int r = 0; r < 4; r++) {
          int c = m0 + wm + mb * 16 + lg * 4 + r;
          float ga = g_lpos[c] * rstd;
          float be = b_lpos[c] - mean * ga;
          int hh = c >> 6, dc = c & 63;
          #pragma unroll
          for (int nb = 0; nb < 2; nb++) {
            int l = wn + nb * 16 + l15;
            float xn = vals[mb][nb][r] * ga + be;
            kT[(((size_t)b * 8 + hh) * 1088 + 1024 + l) * 128 + 64 + dc] = (_Float16)xn;
          }
        }
      }
    }
  } else {
    // ---- qkv: A = qkv_w (1536 x 512), B = xhatT (1024 x 512), tile 128x128 ----
    const int bid = bid0 - 352;
    const int nt = bid & 7, tt = bid >> 3;
    const int mt = tt % 12, b = tt / 12;
    const int m0 = mt * 128, n0 = nt * 128;
    _Float16* ldsA = smem;
    _Float16* ldsB = smem + 16384;
    const _Float16* Abase = w16qkv;
    const _Float16* Bbase = xhatT + (size_t)b * 1024 * 512;
    const int wm = (w >> 1) * 64, wn = (w & 1) * 64;
    MFMA_CORE(512)

    char* tb = (char*)smem;
    if (m0 < 1024) {
      const bool isq = (m0 < 512);
      const float qs = isq ? SCALE2Q : 1.f;
      #pragma unroll
      for (int mb = 0; mb < 4; mb++) {
        #pragma unroll
        for (int r = 0; r < 4; r++) {
          int mcol = wm + mb * 16 + lg * 4 + r;
          float bia = qkv_b[m0 + mcol];
          #pragma unroll
          for (int nb = 0; nb < 4; nb++) {
            int trow = wn + nb * 16 + l15;
            float val = (acc[mb][nb][r] + bia) * qs;
            *(_Float16*)(tb + ((trow * 256 + mcol * 2) ^ ((trow & 7) << 4))) = (_Float16)val;
          }
        }
      }
      __syncthreads();
      #pragma unroll
      for (int it = 0; it < 8; it++) {
        int e = it * 256 + tid;
        int trow = e >> 4, seg = e & 15;
        half8 v = *(const half8*)(tb + ((trow * 256 + seg * 16) ^ ((trow & 7) << 4)));
        if (isq) {
          int mq = m0 + seg * 8, hh = mq >> 6, dc = mq & 63;
          *(half8*)(qT + (((size_t)b * 8 + hh) * 1024 + n0 + trow) * 128 + dc) = v;
        } else {
          int mk = m0 - 512 + seg * 8, hh = mk >> 6, dc = mk & 63;
          *(half8*)(kT + (((size_t)b * 8 + hh) * 1088 + n0 + trow) * 128 + dc) = v;
        }
      }
    } else {
      #pragma unroll
      for (int mb = 0; mb < 4; mb++) {
        #pragma unroll
        for (int r = 0; r < 4; r++) {
          int mrow = wm + mb * 16 + lg * 4 + r;
          float bia = qkv_b[m0 + mrow];
          #pragma unroll
          for (int nb = 0; nb < 4; nb++) {
            int tcol = wn + nb * 16 + l15;
            *(_Float16*)(tb + ((mrow * 256 + tcol * 2) ^ ((mrow & 7) << 4))) =
                (_Float16)(acc[mb][nb][r] + bia);
          }
        }
      }
      __syncthreads();
      #pragma unroll
      for (int it = 0; it < 8; it++) {
        int e = it * 256 + tid;
        int mrow = e >> 4, seg = e & 15;
        half8 v = *(const half8*)(tb + ((mrow * 256 + seg * 16) ^ ((mrow & 7) << 4)));
        int mv = m0 - 1024 + mrow, hh = mv >> 6, dc = mv & 63;
        *(half8*)(vT + (((size_t)b * 8 + hh) * 64 + dc) * 1088 + n0 + seg * 8) = v;
      }
    }
  }
}

// proj: A = proj_w f16 (512 x 512), B = attnT (1024 x 512); 128x128 tile, grid (8,4,8)
__global__ __launch_bounds__(256) void k_mfma_proj(
    const _Float16* __restrict__ Abase, const float* __restrict__ bias,
    const _Float16* __restrict__ Ball, const float* __restrict__ xin,
    float* __restrict__ out)
{
  __shared__ _Float16 smem[32768];   // 64KB: A dbuf [0,16384), B dbuf [16384,32768)
  _Float16* ldsA = smem;
  _Float16* ldsB = smem + 16384;
  const int b = blockIdx.z, mt = blockIdx.y, nt = blockIdx.x;
  const int m0 = mt * 128, n0 = nt * 128;
  const _Float16* Bbase = Ball + (size_t)b * 1024 * 512;
  const int tid = threadIdx.x, lane = tid & 63, w = tid >> 6;
  const int l15 = lane & 15, lg = lane >> 4;
  const int wm = (w >> 1) * 64, wn = (w & 1) * 64;
  MFMA_CORE(512)
  #pragma unroll
  for (int mb = 0; mb < 4; mb++) {
    #pragma unroll
    for (int r = 0; r < 4; r++) {
      int m = m0 + wm + mb * 16 + lg * 4 + r;
      float bia = bias[m];
      #pragma unroll
      for (int nb = 0; nb < 4; nb++) {
        int t = n0 + wn + nb * 16 + l15;
        size_t idx = ((size_t)b * NC + m) * NL1 + t;
        out[idx] = xin[idx] + acc[mb][nb][r] + bia;
      }
    }
  }
}

// ====== ipp GN stats + normalize + scatter fused (f16 input) ======
__global__ __launch_bounds__(256) void k_ipp_fuse(
    const _Float16* __restrict__ raw,
    const float* __restrict__ gm, const float* __restrict__ gb,
    _Float16* __restrict__ qT, _Float16* __restrict__ kT)
{
  const int g = blockIdx.x, b = blockIdx.y;
  const int tid = threadIdx.x;
  const _Float16* p = raw + ((size_t)b * 512 + (size_t)g * 16) * 1024;
  const int t0 = tid * 4;

  float4 v[16];
  float s = 0.f, s2 = 0.f;
  #pragma unroll
  for (int c = 0; c < 16; c++) {
    half4 hv = *(const half4*)&p[(size_t)c * 1024 + t0];
    v[c].x = (float)hv.x; v[c].y = (float)hv.y; v[c].z = (float)hv.z; v[c].w = (float)hv.w;
    s += v[c].x + v[c].y + v[c].z + v[c].w;
    s2 += v[c].x * v[c].x + v[c].y * v[c].y + v[c].z * v[c].z + v[c].w * v[c].w;
  }
  #pragma unroll
  for (int o = 32; o > 0; o >>= 1) { s += __shfl_down(s, o); s2 += __shfl_down(s2, o); }
  __shared__ float rs[4], rq[4], stat[2];
  int lane = tid & 63, w = tid >> 6;
  if (lane == 0) { rs[w] = s; rq[w] = s2; }
  __syncthreads();
  if (tid == 0) {
    float S = rs[0] + rs[1] + rs[2] + rs[3];
    float Q = rq[0] + rq[1] + rq[2] + rq[3];
    float mn = S / 16384.f;
    float var = Q / 16384.f - mn * mn;
    if (var < 0.f) var = 0.f;
    stat[0] = mn; stat[1] = rsqrtf(var + EPSV);
  }
  __syncthreads();
  const float mn = stat[0], rstd = stat[1];

  float ga[16], be[16];
  #pragma unroll
  for (int c = 0; c < 16; c++) {
    ga[c] = gm[g * 16 + c] * rstd;
    be[c] = gb[g * 16 + c] - mn * ga[c];
  }

  const size_t bh = (size_t)b * 8 + (g >> 2);
  const int dcb = (g & 3) * 16;
  #pragma unroll
  for (int j = 0; j < 4; j++) {
    const int t = t0 + j;
    half8 k0, k1, q0, q1;
    #pragma unroll
    for (int c = 0; c < 8; c++) {
      float4 vc = v[c];
      float e = (j == 0) ? vc.x : (j == 1) ? vc.y : (j == 2) ? vc.z : vc.w;
      float xn = e * ga[c] + be[c];
      k0[c] = (_Float16)xn;
      q0[c] = (_Float16)(SCALE2Q * xn);
    }
    #pragma unroll
    for (int c = 8; c < 16; c++) {
      float4 vc = v[c];
      float e = (j == 0) ? vc.x : (j == 1) ? vc.y : (j == 2) ? vc.z : vc.w;
      float xn = e * ga[c] + be[c];
      k1[c - 8] = (_Float16)xn;
      q1[c - 8] = (_Float16)(SCALE2Q * xn);
    }
    _Float16* qd = qT + (bh * 1024 + t) * 128 + 64 + dcb;
    _Float16* kd = kT + (bh * 1088 + t) * 128 + 64 + dcb;
    *(half8*)qd = q0; *(half8*)(qd + 8) = q1;
    *(half8*)kd = k0; *(half8*)(kd + 8) = k1;
  }
}

// ====================== fused attention (32x32 swapped, T15 2-deep pipeline) ======================
// Round-4 proven version (54.5 us): K double-buffered, V triple-buffered,
// permlane32_swap builtin for all lane^32 exchanges.
__global__ __launch_bounds__(256, 2) void k_attn_mfma(
    const _Float16* __restrict__ qT, const _Float16* __restrict__ kT,
    const _Float16* __restrict__ vT, const int* __restrict__ mask,
    _Float16* __restrict__ attnT)
{
  const int x = blockIdx.x & 7;
  const int k = blockIdx.x >> 3;
  const int bh = x + ((k >> 3) << 3);
  const int qt = k & 7;
  const int b = bh >> 3, h = bh & 7;
  const int tid = threadIdx.x;
  const int lane = tid & 63;
  const int w = tid >> 6;
  const int l31 = lane & 31;
  const int hi = lane >> 5;

  __shared__ _Float16 KsB[2 * 64 * 128];   // 32KB, 2 buffers of 8192 halfs
  __shared__ _Float16 VtB[3 * 64 * 64];    // 24KB, 3 buffers of 4096 halfs

  const int q = qt * 128 + w * 32 + l31;

  half8 aq[8];
  {
    const _Float16* qp = qT + ((size_t)bh * 1024 + q) * 128 + hi * 8;
    #pragma unroll
    for (int kst = 0; kst < 8; kst++) aq[kst] = *(const half8*)(qp + kst * 16);
  }

  unsigned int mbits = 0;
  {
    const int* mp = mask + b * 64;
    #pragma unroll
    for (int sb = 0; sb < 2; sb++) {
      #pragma unroll
      for (int reg = 0; reg < 16; reg++) {
        int s = sb * 32 + (reg & 3) + 8 * (reg >> 2) + 4 * hi;
        if (mp[s]) mbits |= 1u << (sb * 16 + reg);
      }
    }
  }

  f32x16 O0 = (f32x16)0.f, O1 = (f32x16)0.f;
  f32x16 scA0 = (f32x16)0.f, scA1 = (f32x16)0.f;
  f32x16 scB0 = (f32x16)0.f, scB1 = (f32x16)0.f;
  float m_run = -INFINITY, l_run = 0.f;

  const int kxor = (l31 & 7) << 4;
  const int ksrow_off = lane >> 4;
  const int kcsrc_base = lane & 15;
  const int vdc_off = lane >> 3;
  const int vcsrc_base = lane & 7;

#define STAGE_KV(T, KD, VD)                                                          \
  {                                                                                  \
    const int s0_ = (T) * 64;                                                        \
    _Pragma("unroll") for (int r = 0; r < 4; r++) {                                  \
      int seg = r * 4 + w;                                                           \
      int srow = seg * 4 + ksrow_off;                                                \
      int csrc = kcsrc_base ^ (srow & 7);                                            \
      gload16(kT + ((size_t)bh * 1088 + s0_ + srow) * 128 + csrc * 8, (KD) + seg * 512); \
    }                                                                                \
    _Pragma("unroll") for (int r = 0; r < 2; r++) {                                  \
      int seg = r * 4 + w;                                                           \
      int dc = seg * 8 + vdc_off;                                                    \
      int csrc = vcsrc_base ^ (dc & 7);                                              \
      gload16(vT + ((size_t)bh * 64 + dc) * 1088 + s0_ + csrc * 8, (VD) + seg * 512);  \
    }                                                                                \
  }

// cross-half (lane^32) reduce via permlane32_swap builtin: OUT = OP(x[l], x[l^32])
#define XHALF_FMAX(OUTV, INV)                                                        \
  { unsigned int xi_ = __float_as_uint(INV);                                         \
    uint32x2 xr_ = __builtin_amdgcn_permlane32_swap(xi_, xi_, false, false);         \
    OUTV = fmaxf(__uint_as_float(xr_.x), __uint_as_float(xr_.y)); }
#define XHALF_ADD(OUTV, INV)                                                         \
  { unsigned int xi_ = __float_as_uint(INV);                                         \
    uint32x2 xr_ = __builtin_amdgcn_permlane32_swap(xi_, xi_, false, false);         \
    OUTV = __uint_as_float(xr_.x) + __uint_as_float(xr_.y); }

#define ATTN_ITER(C0, C1, P0, P1, T)                                                 \
  {                                                                                  \
    const int T_ = (T);                                                              \
    if (T_ <= 16) {                                                                  \
      if (T_ <= 15) {                                                                \
        _Float16* kd_ = KsB + (((T_ + 1) & 1) << 13);                                \
        _Float16* vd_ = VtB + ((T_ + 1) % 3) * 4096;                                 \
        STAGE_KV(T_ + 1, kd_, vd_)                                                   \
      }                                                                              \
      const char* ksb_ = (const char*)(KsB + ((T_ & 1) << 13));                      \
      C0 = (f32x16)0.f; C1 = (f32x16)0.f;                                            \
      __builtin_amdgcn_s_setprio(1);                                                 \
      _Pragma("unroll") for (int kst = 0; kst < 8; kst++) {                          \
        half8 kf0 = *(const half8*)(ksb_ + ((l31 * 256 + kst * 32 + hi * 16) ^ kxor)); \
        half8 kf1 = *(const half8*)(ksb_ + (((32 + l31) * 256 + kst * 32 + hi * 16) ^ kxor)); \
        C0 = __builtin_amdgcn_mfma_f32_32x32x16_f16(kf0, aq[kst], C0, 0, 0, 0);      \
        C1 = __builtin_amdgcn_mfma_f32_32x32x16_f16(kf1, aq[kst], C1, 0, 0, 0);      \
      }                                                                              \
      __builtin_amdgcn_s_setprio(0);                                                 \
    }                                                                                \
    if (T_ >= 1) {                                                                   \
      if (T_ == 17) {                                                                \
        _Pragma("unroll") for (int i = 0; i < 16; i++) {                             \
          if ((mbits >> i) & 1)        P0[i] = -INFINITY;                            \
          if ((mbits >> (16 + i)) & 1) P1[i] = -INFINITY;                            \
        }                                                                            \
      }                                                                              \
      float mx;                                                                      \
      {                                                                              \
        float a0 = fmaxf(fmaxf(P0[0], P0[1]), P0[2]);                                \
        float a1 = fmaxf(fmaxf(P0[3], P0[4]), P0[5]);                                \
        float a2 = fmaxf(fmaxf(P0[6], P0[7]), P0[8]);                                \
        float a3 = fmaxf(fmaxf(P0[9], P0[10]), P0[11]);                              \
        float a4 = fmaxf(fmaxf(P0[12], P0[13]), P0[14]);                             \
        float a5 = fmaxf(fmaxf(P0[15], P1[0]), P1[1]);                               \
        float a6 = fmaxf(fmaxf(P1[2], P1[3]), P1[4]);                                \
        float a7 = fmaxf(fmaxf(P1[5], P1[6]), P1[7]);                                \
        float a8 = fmaxf(fmaxf(P1[8], P1[9]), P1[10]);                               \
        float a9 = fmaxf(fmaxf(P1[11], P1[12]), P1[13]);                             \
        float aa = fmaxf(P1[14], P1[15]);                                            \
        float b0 = fmaxf(fmaxf(a0, a1), a2);                                         \
        float b1 = fmaxf(fmaxf(a3, a4), a5);                                         \
        float b2 = fmaxf(fmaxf(a6, a7), a8);                                         \
        float b3 = fmaxf(a9, aa);                                                    \
        mx = fmaxf(fmaxf(b0, b1), fmaxf(b2, b3));                                    \
      }                                                                              \
      XHALF_FMAX(mx, mx)                                                             \
      if (__all(mx <= m_run + DEFER_THR)) {                                          \
        float sum = 0.f;                                                             \
        _Pragma("unroll") for (int i = 0; i < 16; i++) {                             \
          float p = fast_exp2(P0[i] - m_run); P0[i] = p; sum += p; }                 \
        _Pragma("unroll") for (int i = 0; i < 16; i++) {                             \
          float p = fast_exp2(P1[i] - m_run); P1[i] = p; sum += p; }                 \
        XHALF_ADD(sum, sum)                                                          \
        l_run += sum;                                                                \
      } else {                                                                       \
        float m_new = fmaxf(m_run, mx);                                              \
        float alpha = fast_exp2(m_run - m_new);                                      \
        float sum = 0.f;                                                             \
        _Pragma("unroll") for (int i = 0; i < 16; i++) {                             \
          float p = fast_exp2(P0[i] - m_new); P0[i] = p; sum += p; }                 \
        _Pragma("unroll") for (int i = 0; i < 16; i++) {                             \
          float p = fast_exp2(P1[i] - m_new); P1[i] = p; sum += p; }                 \
        XHALF_ADD(sum, sum)                                                          \
        l_run = l_run * alpha + sum;                                                 \
        m_run = m_new;                                                               \
        _Pragma("unroll") for (int i = 0; i < 16; i++) { O0[i] *= alpha; O1[i] *= alpha; } \
      }                                                                              \
      const char* vtb_ = (const char*)(VtB + ((T_ - 1) % 3) * 4096);                 \
      __builtin_amdgcn_s_setprio(1);                                                 \
      _Pragma("unroll") for (int sb = 0; sb < 2; sb++) {                             \
        _Pragma("unroll") for (int k2 = 0; k2 < 2; k2++) {                           \
          const int kst = sb * 2 + k2;                                               \
          unsigned int pa0, pa1, pb0, pb1;                                           \
          if (sb == 0) {                                                             \
            pa0 = pkrtz(P0[8 * k2 + 0], P0[8 * k2 + 1]);                             \
            pa1 = pkrtz(P0[8 * k2 + 2], P0[8 * k2 + 3]);                             \
            pb0 = pkrtz(P0[8 * k2 + 4], P0[8 * k2 + 5]);                             \
            pb1 = pkrtz(P0[8 * k2 + 6], P0[8 * k2 + 7]);                             \
          } else {                                                                   \
            pa0 = pkrtz(P1[8 * k2 + 0], P1[8 * k2 + 1]);                             \
            pa1 = pkrtz(P1[8 * k2 + 2], P1[8 * k2 + 3]);                             \
            pb0 = pkrtz(P1[8 * k2 + 4], P1[8 * k2 + 5]);                             \
            pb1 = pkrtz(P1[8 * k2 + 6], P1[8 * k2 + 7]);                             \
          }                                                                          \
          uint32x2 r0_ = __builtin_amdgcn_permlane32_swap(pa0, pb0, false, false);   \
          uint32x2 r1_ = __builtin_amdgcn_permlane32_swap(pa1, pb1, false, false);   \
          union { unsigned int u[4]; half8 hh; } pf;                                 \
          pf.u[0] = r0_.x;                                                           \
          pf.u[1] = r1_.x;                                                           \
          pf.u[2] = r0_.y;                                                           \
          pf.u[3] = r1_.y;                                                           \
          half8 vf0 = *(const half8*)(vtb_ + ((l31 * 128 + kst * 32 + hi * 16) ^ kxor)); \
          half8 vf1 = *(const half8*)(vtb_ + (((32 + l31) * 128 + kst * 32 + hi * 16) ^ kxor)); \
          O0 = __builtin_amdgcn_mfma_f32_32x32x16_f16(vf0, pf.hh, O0, 0, 0, 0);      \
          O1 = __builtin_amdgcn_mfma_f32_32x32x16_f16(vf1, pf.hh, O1, 0, 0, 0);      \
        }                                                                            \
      }                                                                              \
      __builtin_amdgcn_s_setprio(0);                                                 \
    }                                                                                \
    if (T_ < 17) {                                                                   \
      asm volatile("s_waitcnt vmcnt(0)" ::: "memory");                               \
      __builtin_amdgcn_s_barrier();                                                  \
    }                                                                                \
  }

  STAGE_KV(0, KsB, VtB)
  asm volatile("s_waitcnt vmcnt(0)" ::: "memory");
  __builtin_amdgcn_s_barrier();

  for (int t = 0; t < 18; t += 2) {
    ATTN_ITER(scA0, scA1, scB0, scB1, t)
    ATTN_ITER(scB0, scB1, scA0, scA1, t + 1)
  }

  float inv = 1.f / l_run;
  _Float16* op = attnT + ((size_t)b * 1024 + q) * 512 + h * 64;
  #pragma unroll
  for (int i = 0; i < 16; i += 2) {
    int dc = (i & 3) + 8 * (i >> 2) + 4 * hi;
    unsigned int c0 = pkrtz(O0[i] * inv, O0[i + 1] * inv);
    unsigned int c1 = pkrtz(O1[i] * inv, O1[i + 1] * inv);
    *(unsigned int*)(op + dc) = c0;
    *(unsigned int*)(op + 32 + dc) = c1;
  }
}

// ============================ launcher ============================
extern "C" void kernel_launch(void* const* d_in, const int* in_sizes, int n_in,
                              void* d_out, int out_size, void* d_ws, size_t ws_size,
                              hipStream_t stream) {
  const float* x         = (const float*)d_in[0];
  const float* xf_out    = (const float*)d_in[1];
  const float* obj_class = (const float*)d_in[2];
  const float* obj_bbox  = (const float*)d_in[3];
  const float* ipbe      = (const float*)d_in[4];
  const int*   mask      = (const int*)d_in[5];
  const float* qkv_w     = (const float*)d_in[6];
  const float* qkv_b     = (const float*)d_in[7];
  const float* g_qkv     = (const float*)d_in[8];
  const float* b_qkv     = (const float*)d_in[9];
  const float* lc_w      = (const float*)d_in[10];
  const float* lc_b      = (const float*)d_in[11];
  const float* lp_w      = (const float*)d_in[12];
  const float* lp_b      = (const float*)d_in[13];
  const float* g_obj     = (const float*)d_in[14];
  const float* b_obj     = (const float*)d_in[15];
  const float* g_lpos    = (const float*)d_in[16];
  const float* b_lpos    = (const float*)d_in[17];
  const float* g_ipos    = (const float*)d_in[18];
  const float* b_ipos    = (const float*)d_in[19];
  const float* proj_w    = (const float*)d_in[20];
  const float* proj_b    = (const float*)d_in[21];
  float* out = (float*)d_out;

  _Float16* f16b = (_Float16*)d_ws;
  _Float16* qT      = f16b;                      // 8,388,608
  _Float16* kT      = qT + 8388608;              // 8,912,896
  _Float16* vT      = kT + 8912896;              // 4,456,448
  _Float16* xhatT   = vT + 4456448;              // 4,194,304
  _Float16* ipbeT   = xhatT + 4194304;           // 8,388,608
  _Float16* attnT   = ipbeT + 8388608;           // 4,194,304
  _Float16* w16qkv  = attnT + 4194304;           //   786,432
  _Float16* w16lp   = w16qkv + 786432;           //   524,288
  _Float16* w16proj = w16lp + 524288;            //   262,144
  _Float16* w16lc   = w16proj + 262144;          // 1,048,576
  _Float16* lceT    = w16lc + 1048576;           //   524,288
  _Float16* objT    = lceT + 524288;             //   524,288
  _Float16* ipp16   = objT + 524288;             // 4,194,304
  float* st = (float*)(ipp16 + 4194304);
  float* xm = st, * xr = st + 256, * om = st + 512, * orr = st + 768;

  dim3 blk(256);
  k_init<<<dim3(3072), blk, 0, stream>>>(x, obj_class, xm, xr, om, orr,
                                         qkv_w, w16qkv, lp_w, w16lp, proj_w, w16proj, lc_w, w16lc);
  k_prep<<<dim3(3328), blk, 0, stream>>>(x, xm, xr, g_qkv, b_qkv, xhatT,
                                         ipbe, ipbeT,
                                         xf_out, obj_class, obj_bbox, om, orr, g_obj, b_obj,
                                         lceT, objT);
  k_mfma_big<<<dim3(1120), blk, 0, stream>>>(w16qkv, qkv_b, xhatT,
                                             w16lp, lp_b, ipbeT,
                                             w16lc, lc_b, lceT, objT,
                                             g_lpos, b_lpos,
                                             qT, kT, vT, ipp16);
  k_ipp_fuse<<<dim3(32, 8), blk, 0, stream>>>(ipp16, g_ipos, b_ipos, qT, kT);
  k_attn_mfma<<<dim3(512), blk, 0, stream>>>(qT, kT, vT, mask, attnT);
  k_mfma_proj<<<dim3(8, 4, 8), blk, 0, stream>>>(w16proj, proj_b, attnT, x, out);
}

// Round 8
// 125.276 us; speedup vs baseline: 1.1006x; 1.0032x over previous
//
#include <hip/hip_runtime.h>
#include <math.h>

#define NB 8
#define NC 512
#define NL1 1024
#define NL2 64
#define NLKV 1088
#define NENC 1024
#define EPSV 1e-5f
#define SCALE2 0.08838834764831845f          // 1/sqrt(128)
#define SCALE2Q 0.12752425f                  // SCALE2 * log2(e)
#define DEFER_THR 11.5415603f                // 8 nats in log2 units

typedef _Float16 half8 __attribute__((ext_vector_type(8)));
typedef _Float16 half4 __attribute__((ext_vector_type(4)));
typedef __fp16 fp16x2 __attribute__((ext_vector_type(2)));
typedef float f32x4 __attribute__((ext_vector_type(4)));
typedef float f32x16 __attribute__((ext_vector_type(16)));
typedef unsigned int uint32x2 __attribute__((ext_vector_type(2)));

__device__ __forceinline__ void gload16(const _Float16* g, _Float16* l) {
  __builtin_amdgcn_global_load_lds(
      (const __attribute__((address_space(1))) void*)g,
      (__attribute__((address_space(3))) void*)l, 16, 0, 0);
}

__device__ __forceinline__ unsigned int pkrtz(float a, float b) {
  union { fp16x2 hh; unsigned int uu; } cv;
  cv.hh = __builtin_amdgcn_cvt_pkrtz(a, b);
  return cv.uu;
}

__device__ __forceinline__ float fast_exp2(float x) {
  return __builtin_amdgcn_exp2f(x);
}

// ========== k_init: GN stats (x, obj_class) + all 4 weight converts ==========
__global__ __launch_bounds__(256) void k_init(
    const float* __restrict__ x, const float* __restrict__ obj,
    float* __restrict__ xm, float* __restrict__ xr,
    float* __restrict__ om, float* __restrict__ orr,
    const float* __restrict__ qkv_w, _Float16* __restrict__ w16qkv,
    const float* __restrict__ lp_w, _Float16* __restrict__ w16lp,
    const float* __restrict__ proj_w, _Float16* __restrict__ w16proj,
    const float* __restrict__ lc_w, _Float16* __restrict__ w16lc)
{
  int bid = blockIdx.x;
  if (bid < 512) {
    const float* p; float* meanp; float* rstdp; int n4, n, bg;
    if (bid < 256) {
      bg = bid;
      int b = bg >> 5, g = bg & 31;
      p = x + ((size_t)b * 512 + (size_t)g * 16) * 1024;
      n = 16 * 1024; meanp = xm; rstdp = xr;
    } else {
      bg = bid - 256;
      int b = bg >> 5, g = bg & 31;
      p = obj + ((size_t)b * 1024 + (size_t)g * 32) * 64;
      n = 32 * 64; meanp = om; rstdp = orr;
    }
    n4 = n >> 2;
    float s = 0.f, s2 = 0.f;
    for (int i = threadIdx.x; i < n4; i += 256) {
      float4 v = ((const float4*)p)[i];
      s += v.x + v.y + v.z + v.w;
      s2 += v.x * v.x + v.y * v.y + v.z * v.z + v.w * v.w;
    }
    #pragma unroll
    for (int o = 32; o > 0; o >>= 1) { s += __shfl_down(s, o); s2 += __shfl_down(s2, o); }
    __shared__ float rs[4], rq[4];
    int lane = threadIdx.x & 63, w = threadIdx.x >> 6;
    if (lane == 0) { rs[w] = s; rq[w] = s2; }
    __syncthreads();
    if (threadIdx.x == 0) {
      float S = rs[0] + rs[1] + rs[2] + rs[3];
      float Q = rq[0] + rq[1] + rq[2] + rq[3];
      float m = S / n;
      float v = Q / n - m * m;
      if (v < 0.f) v = 0.f;
      meanp[bg] = m;
      rstdp[bg] = rsqrtf(v + EPSV);
    }
  } else {
    int cb = bid - 512;
    const float* s; _Float16* d; int i4;
    if (cb < 768)        { s = qkv_w;  d = w16qkv;  i4 = cb * 256 + threadIdx.x; }
    else if (cb < 1280)  { s = lp_w;   d = w16lp;   i4 = (cb - 768) * 256 + threadIdx.x; }
    else if (cb < 1536)  { s = proj_w; d = w16proj; i4 = (cb - 1280) * 256 + threadIdx.x; }
    else                 { s = lc_w;   d = w16lc;   i4 = (cb - 1536) * 256 + threadIdx.x; }
    float4 v = *(const float4*)&s[(size_t)i4 * 4];
    half4 o; o.x = (_Float16)v.x; o.y = (_Float16)v.y; o.z = (_Float16)v.z; o.w = (_Float16)v.w;
    *(half4*)&d[(size_t)i4 * 4] = o;
  }
}

// ========== k_prep: gn_xT (1024) + ipbeT (2048) + lceobjT (256) ==========
__global__ __launch_bounds__(256) void k_prep(
    const float* __restrict__ x, const float* __restrict__ xm, const float* __restrict__ xr,
    const float* __restrict__ g_qkv, const float* __restrict__ b_qkv, _Float16* __restrict__ xT,
    const float* __restrict__ ipbe, _Float16* __restrict__ ipbeT,
    const float* __restrict__ xf_out, const float* __restrict__ obj_class,
    const float* __restrict__ obj_bbox,
    const float* __restrict__ om, const float* __restrict__ orr,
    const float* __restrict__ g_obj, const float* __restrict__ b_obj,
    _Float16* __restrict__ lceT, _Float16* __restrict__ objT)
{
  __shared__ _Float16 tile[64][72];
  const int bid = blockIdx.x;
  const int tl = threadIdx.x & 63;
  if (bid < 1024) {
    const int tt = bid & 15, ct = (bid >> 4) & 7, b = bid >> 7;
    const int c0 = ct * 64, t0 = tt * 64;
    const int cp = threadIdx.x >> 6;
    #pragma unroll
    for (int i = 0; i < 16; i++) {
      int c = c0 + i * 4 + cp;
      float v = x[((size_t)b * NC + c) * NL1 + t0 + tl];
      int g = c >> 4;
      float ga = g_qkv[c] * xr[b * 32 + g];
      float be = b_qkv[c] - xm[b * 32 + g] * ga;
      tile[tl][i * 4 + cp] = (_Float16)(v * ga + be);
    }
    __syncthreads();
    int tr = threadIdx.x >> 2, c16 = (threadIdx.x & 3) * 16;
    _Float16* dst = xT + ((size_t)b * 1024 + t0 + tr) * 512 + c0 + c16;
    *(half8*)dst = *(half8*)&tile[tr][c16];
    *(half8*)(dst + 8) = *(half8*)&tile[tr][c16 + 8];
  } else if (bid < 3072) {
    const int e2 = bid - 1024;
    const int tt = e2 & 15, et = (e2 >> 4) & 15, b = e2 >> 8;
    const int e0 = et * 64, t0 = tt * 64;
    const int ep = threadIdx.x >> 6;
    #pragma unroll
    for (int i = 0; i < 16; i++) {
      int e = e0 + i * 4 + ep;
      tile[tl][i * 4 + ep] = (_Float16)ipbe[((size_t)b * 1024 + e) * 1024 + t0 + tl];
    }
    __syncthreads();
    int tr = threadIdx.x >> 2, c16 = (threadIdx.x & 3) * 16;
    _Float16* d = ipbeT + ((size_t)b * 1024 + t0 + tr) * 1024 + e0 + c16;
    *(half8*)d = *(half8*)&tile[tr][c16];
    *(half8*)(d + 8) = *(half8*)&tile[tr][c16 + 8];
  } else {
    const int e2 = bid - 3072;
    const int et = e2 & 15, which = (e2 >> 4) & 1, b = e2 >> 5;
    const int e0 = et * 64;
    const int ep = threadIdx.x >> 6;
    if (which == 0) {
      #pragma unroll
      for (int i = 0; i < 16; i++) {
        int e = e0 + i * 4 + ep;
        size_t idx = ((size_t)b * 1024 + e) * 64 + tl;
        int g = e >> 5;
        float xn = (obj_class[idx] - om[b * 32 + g]) * orr[b * 32 + g] * g_obj[e] + b_obj[e];
        tile[tl][i * 4 + ep] = (_Float16)(0.5f * (xf_out[idx] + xn));
      }
    } else {
      #pragma unroll
      for (int i = 0; i < 16; i++) {
        int e = e0 + i * 4 + ep;
        tile[tl][i * 4 + ep] = (_Float16)obj_bbox[((size_t)b * 1024 + e) * 64 + tl];
      }
    }
    __syncthreads();
    int tr = threadIdx.x >> 2, c16 = (threadIdx.x & 3) * 16;
    _Float16* dst = (which == 0 ? lceT : objT) + ((size_t)b * 64 + tr) * 1024 + e0 + c16;
    *(half8*)dst = *(half8*)&tile[tr][c16];
    *(half8*)(dst + 8) = *(half8*)&tile[tr][c16 + 8];
  }
}

// =================== MFMA GEMM cores (2-phase, counted-vmcnt split barrier) ===================
// T4: stage(t+1) -> vmcnt(8|6) [drains only tile-t loads; t+1 stays in flight] ->
// s_barrier -> ds_read+MFMA -> s_barrier. Replaces __syncthreads' full vmcnt(0)
// drain, which serialized prefetch completion against every K-step.
#define MFMA_CORE(KTOT)                                                                  \
  f32x4 acc[4][4];                                                                       \
  _Pragma("unroll") for (int i_ = 0; i_ < 4; i_++)                                       \
      _Pragma("unroll") for (int j_ = 0; j_ < 4; j_++) acc[i_][j_] = (f32x4)0.f;         \
  {                                                                                      \
    const int rsub = lane >> 3, csrc = (lane & 7) ^ rsub;                                \
    const int NT_ = (KTOT) / 64;                                                         \
    _Pragma("unroll") for (int i = 0; i < 4; i++) {                                      \
      int seg = w * 4 + i;                                                               \
      int row = seg * 8 + rsub;                                                          \
      gload16(Abase + (size_t)(m0 + row) * (KTOT) + csrc * 8, ldsA + seg * 512);         \
      gload16(Bbase + (size_t)(n0 + row) * (KTOT) + csrc * 8, ldsB + seg * 512);         \
    }                                                                                    \
    int cur_ = 0;                                                                        \
    for (int t_ = 0; t_ < NT_; t_++) {                                                   \
      if (t_ + 1 < NT_) {                                                                \
        _Float16* da_ = ldsA + ((cur_ ^ 1) << 13);                                       \
        _Float16* db_ = ldsB + ((cur_ ^ 1) << 13);                                       \
        int kt = (t_ + 1) * 64;                                                          \
        _Pragma("unroll") for (int i = 0; i < 4; i++) {                                  \
          int seg = w * 4 + i;                                                           \
          int row = seg * 8 + rsub;                                                      \
          gload16(Abase + (size_t)(m0 + row) * (KTOT) + kt + csrc * 8, da_ + seg * 512); \
          gload16(Bbase + (size_t)(n0 + row) * (KTOT) + kt + csrc * 8, db_ + seg * 512); \
        }                                                                                \
        asm volatile("s_waitcnt vmcnt(8)" ::: "memory");                                 \
      } else {                                                                           \
        asm volatile("s_waitcnt vmcnt(0)" ::: "memory");                                 \
      }                                                                                  \
      __builtin_amdgcn_s_barrier();                                                      \
      const char* ra_ = (const char*)(ldsA + (cur_ << 13));                              \
      const char* rb_ = (const char*)(ldsB + (cur_ << 13));                              \
      _Pragma("unroll") for (int kk = 0; kk < 2; kk++) {                                 \
        half8 af[4], bf[4];                                                              \
        _Pragma("unroll") for (int mb = 0; mb < 4; mb++) {                               \
          int row = wm + mb * 16 + l15;                                                  \
          af[mb] = *(const half8*)(ra_ + row * 128 +                                     \
                                   ((kk * 64 + lg * 16) ^ ((row & 7) << 4)));            \
        }                                                                                \
        _Pragma("unroll") for (int nb = 0; nb < 4; nb++) {                               \
          int row = wn + nb * 16 + l15;                                                  \
          bf[nb] = *(const half8*)(rb_ + row * 128 +                                     \
                                   ((kk * 64 + lg * 16) ^ ((row & 7) << 4)));            \
        }                                                                                \
        _Pragma("unroll") for (int mb = 0; mb < 4; mb++)                                 \
            _Pragma("unroll") for (int nb = 0; nb < 4; nb++)                             \
                acc[mb][nb] = __builtin_amdgcn_mfma_f32_16x16x32_f16(af[mb], bf[nb],     \
                                                                    acc[mb][nb], 0, 0, 0);\
      }                                                                                  \
      __builtin_amdgcn_s_barrier();                                                      \
      cur_ ^= 1;                                                                         \
    }                                                                                    \
  }

#define MFMA_CORE_N64(KTOT)                                                              \
  f32x4 acc[4][2];                                                                       \
  _Pragma("unroll") for (int i_ = 0; i_ < 4; i_++)                                       \
      _Pragma("unroll") for (int j_ = 0; j_ < 2; j_++) acc[i_][j_] = (f32x4)0.f;         \
  {                                                                                      \
    const int rsub = lane >> 3, csrc = (lane & 7) ^ rsub;                                \
    const int NT_ = (KTOT) / 64;                                                         \
    _Pragma("unroll") for (int i = 0; i < 4; i++) {                                      \
      int seg = w * 4 + i;                                                               \
      int row = seg * 8 + rsub;                                                          \
      gload16(Abase + (size_t)(m0 + row) * (KTOT) + csrc * 8, ldsA + seg * 512);         \
    }                                                                                    \
    _Pragma("unroll") for (int i = 0; i < 2; i++) {                                      \
      int seg = w * 2 + i;                                                               \
      int row = seg * 8 + rsub;                                                          \
      gload16(Bbase + (size_t)row * (KTOT) + csrc * 8, ldsB + seg * 512);                \
    }                                                                                    \
    int cur_ = 0;                                                                        \
    for (int t_ = 0; t_ < NT_; t_++) {                                                   \
      if (t_ + 1 < NT_) {                                                                \
        _Float16* da_ = ldsA + ((cur_ ^ 1) << 13);                                       \
        _Float16* db_ = ldsB + ((cur_ ^ 1) << 12);                                       \
        int kt = (t_ + 1) * 64;                                                          \
        _Pragma("unroll") for (int i = 0; i < 4; i++) {                                  \
          int seg = w * 4 + i;                                                           \
          int row = seg * 8 + rsub;                                                      \
          gload16(Abase + (size_t)(m0 + row) * (KTOT) + kt + csrc * 8, da_ + seg * 512); \
        }                                                                                \
        _Pragma("unroll") for (int i = 0; i < 2; i++) {                                  \
          int seg = w * 2 + i;                                                           \
          int row = seg * 8 + rsub;                                                      \
          gload16(Bbase + (size_t)row * (KTOT) + kt + csrc * 8, db_ + seg * 512);        \
        }                                                                                \
        asm volatile("s_waitcnt vmcnt(6)" ::: "memory");                                 \
      } else {                                                                           \
        asm volatile("s_waitcnt vmcnt(0)" ::: "memory");                                 \
      }                                                                                  \
      __builtin_amdgcn_s_barrier();                                                      \
      const char* ra_ = (const char*)(ldsA + (cur_ << 13));                              \
      const char* rb_ = (const char*)(ldsB + (cur_ << 12));                              \
      _Pragma("unroll") for (int kk = 0; kk < 2; kk++) {                                 \
        half8 af[4], bf[2];                                                              \
        _Pragma("unroll") for (int mb = 0; mb < 4; mb++) {                               \
          int row = wm + mb * 16 + l15;                                                  \
          af[mb] = *(const half8*)(ra_ + row * 128 +                                     \
                                   ((kk * 64 + lg * 16) ^ ((row & 7) << 4)));            \
        }                                                                                \
        _Pragma("unroll") for (int nb = 0; nb < 2; nb++) {                               \
          int row = wn + nb * 16 + l15;                                                  \
          bf[nb] = *(const half8*)(rb_ + row * 128 +                                     \
                                   ((kk * 64 + lg * 16) ^ ((row & 7) << 4)));            \
        }                                                                                \
        _Pragma("unroll") for (int mb = 0; mb < 4; mb++)                                 \
            _Pragma("unroll") for (int nb = 0; nb < 2; nb++)                             \
                acc[mb][nb] = __builtin_amdgcn_mfma_f32_16x16x32_f16(af[mb], bf[nb],     \
                                                                    acc[mb][nb], 0, 0, 0);\
      }                                                                                  \
      __builtin_amdgcn_s_barrier();                                                      \
      cur_ ^= 1;                                                                         \
    }                                                                                    \
  }

// ====== k_mfma_big: ipp [0,256) + lc/lpe [256,352) + qkv [352,1120) ======
__global__ __launch_bounds__(256) void k_mfma_big(
    const _Float16* __restrict__ w16qkv, const float* __restrict__ qkv_b,
    const _Float16* __restrict__ xhatT,
    const _Float16* __restrict__ w16lp, const float* __restrict__ lp_b,
    const _Float16* __restrict__ ipbeT,
    const _Float16* __restrict__ w16lc, const float* __restrict__ lc_b,
    const _Float16* __restrict__ lceT, const _Float16* __restrict__ objT,
    const float* __restrict__ g_lpos, const float* __restrict__ b_lpos,
    _Float16* __restrict__ qT, _Float16* __restrict__ kT, _Float16* __restrict__ vT,
    _Float16* __restrict__ ipp16)
{
  __shared__ _Float16 smem[32768];   // 64KB: A dbuf [0,16384), B dbuf [16384,32768)
  const int bid0 = blockIdx.x;
  const int tid = threadIdx.x, lane = tid & 63, w = tid >> 6;
  const int l15 = lane & 15, lg = lane >> 4;

  if (bid0 < 256) {
    // ---- ipp: A = lp_w (512 x 1024), B = ipbeT, tile 128x128 ----
    const int nt = bid0 & 7, mt = (bid0 >> 3) & 3, b = bid0 >> 5;
    const int m0 = mt * 128, n0 = nt * 128;
    _Float16* ldsA = smem;
    _Float16* ldsB = smem + 16384;
    const _Float16* Abase = w16lp;
    const _Float16* Bbase = ipbeT + (size_t)b * 1024 * 1024;
    const int wm = (w >> 1) * 64, wn = (w & 1) * 64;
    MFMA_CORE(1024)
    #pragma unroll
    for (int mb = 0; mb < 4; mb++) {
      #pragma unroll
      for (int r = 0; r < 4; r++) {
        int m = m0 + wm + mb * 16 + lg * 4 + r;
        float bia = lp_b[m];
        #pragma unroll
        for (int nb = 0; nb < 4; nb++) {
          int t = n0 + wn + nb * 16 + l15;
          ipp16[((size_t)b * NC + m) * NL1 + t] = (_Float16)(acc[mb][nb][r] + bia);
        }
      }
    }
  } else if (bid0 < 352) {
    // ---- lc/lpe: tile 128x64, K=1024; lpe fuses GroupNorm ----
    const int local = bid0 - 256;
    const int mt = local % 12, b = local / 12;
    const bool islc = (mt < 8);
    const int m0 = (islc ? mt : mt - 8) * 128;
    _Float16* ldsA = smem;
    _Float16* ldsB = smem + 16384;
    float (*red_s)[4] = (float(*)[4])(smem + 24576);
    float (*red_q)[4] = (float(*)[4])(smem + 24608);
    const _Float16* Abase = islc ? w16lc : w16lp;
    const float* bias = islc ? lc_b : lp_b;
    const _Float16* Bbase = (islc ? lceT : objT) + (size_t)b * 64 * 1024;
    const int wm = (w >> 1) * 64, wn = (w & 1) * 32;
    MFMA_CORE_N64(1024)

    if (islc) {
      #pragma unroll
      for (int mb = 0; mb < 4; mb++) {
        #pragma unroll
        for (int r = 0; r < 4; r++) {
          int m = m0 + wm + mb * 16 + lg * 4 + r;
          float bia = bias[m];
          #pragma unroll
          for (int nb = 0; nb < 2; nb++) {
            int l = wn + nb * 16 + l15;
            float val = acc[mb][nb][r] + bia;
            if (m < 512) {
              int h = m >> 6, dc = m & 63;
              kT[(((size_t)b * 8 + h) * 1088 + 1024 + l) * 128 + dc] = (_Float16)val;
            } else {
              int mv = m - 512, h = mv >> 6, dc = mv & 63;
              vT[(((size_t)b * 8 + h) * 64 + dc) * 1088 + 1024 + l] = (_Float16)val;
            }
          }
        }
      }
    } else {
      float vals[4][2][4];
      float ps[4], pq[4];
      #pragma unroll
      for (int mb = 0; mb < 4; mb++) {
        ps[mb] = 0.f; pq[mb] = 0.f;
        #pragma unroll
        for (int r = 0; r < 4; r++) {
          int m = m0 + wm + mb * 16 + lg * 4 + r;
          float bia = bias[m];
          #pragma unroll
          for (int nb = 0; nb < 2; nb++) {
            float val = acc[mb][nb][r] + bia;
            vals[mb][nb][r] = val;
            ps[mb] += val; pq[mb] += val * val;
          }
        }
      }
      #pragma unroll
      for (int mb = 0; mb < 4; mb++) {
        #pragma unroll
        for (int o = 32; o > 0; o >>= 1) {
          ps[mb] += __shfl_xor(ps[mb], o);
          pq[mb] += __shfl_xor(pq[mb], o);
        }
      }
      if (lane == 0) {
        #pragma unroll
        for (int mb = 0; mb < 4; mb++) { red_s[w][mb] = ps[mb]; red_q[w][mb] = pq[mb]; }
      }
      __syncthreads();
      const int wbase = (wm >> 6) * 2;
      #pragma unroll
      for (int mb = 0; mb < 4; mb++) {
        float S = red_s[wbase][mb] + red_s[wbase + 1][mb];
        float Q = red_q[wbase][mb] + red_q[wbase + 1][mb];
        float mean = S * (1.f / 1024.f);
        float var = Q * (1.f / 1024.f) - mean * mean;
        if (var < 0.f) var = 0.f;
        float rstd = rsqrtf(var + EPSV);
        #pragma unroll
        for (int r = 0; r < 4; r++) {
          int c = m0 + wm + mb * 16 + lg * 4 + r;
          float ga = g_lpos[c] * rstd;
          float be = b_lpos[c] - mean * ga;
          int hh = c >> 6, dc = c & 63;
          #pragma unroll
          for (int nb = 0; nb < 2; nb++) {
            int l = wn + nb * 16 + l15;
            float xn = vals[mb][nb][r] * ga + be;
            kT[(((size_t)b * 8 + hh) * 1088 + 1024 + l) * 128 + 64 + dc] = (_Float16)xn;
          }
        }
      }
    }
  } else {
    // ---- qkv: A = qkv_w (1536 x 512), B = xhatT (1024 x 512), tile 128x128 ----
    const int bid = bid0 - 352;
    const int nt = bid & 7, tt = bid >> 3;
    const int mt = tt % 12, b = tt / 12;
    const int m0 = mt * 128, n0 = nt * 128;
    _Float16* ldsA = smem;
    _Float16* ldsB = smem + 16384;
    const _Float16* Abase = w16qkv;
    const _Float16* Bbase = xhatT + (size_t)b * 1024 * 512;
    const int wm = (w >> 1) * 64, wn = (w & 1) * 64;
    MFMA_CORE(512)

    char* tb = (char*)smem;
    if (m0 < 1024) {
      const bool isq = (m0 < 512);
      const float qs = isq ? SCALE2Q : 1.f;
      #pragma unroll
      for (int mb = 0; mb < 4; mb++) {
        #pragma unroll
        for (int r = 0; r < 4; r++) {
          int mcol = wm + mb * 16 + lg * 4 + r;
          float bia = qkv_b[m0 + mcol];
          #pragma unroll
          for (int nb = 0; nb < 4; nb++) {
            int trow = wn + nb * 16 + l15;
            float val = (acc[mb][nb][r] + bia) * qs;
            *(_Float16*)(tb + ((trow * 256 + mcol * 2) ^ ((trow & 7) << 4))) = (_Float16)val;
          }
        }
      }
      __syncthreads();
      #pragma unroll
      for (int it = 0; it < 8; it++) {
        int e = it * 256 + tid;
        int trow = e >> 4, seg = e & 15;
        half8 v = *(const half8*)(tb + ((trow * 256 + seg * 16) ^ ((trow & 7) << 4)));
        if (isq) {
          int mq = m0 + seg * 8, hh = mq >> 6, dc = mq & 63;
          *(half8*)(qT + (((size_t)b * 8 + hh) * 1024 + n0 + trow) * 128 + dc) = v;
        } else {
          int mk = m0 - 512 + seg * 8, hh = mk >> 6, dc = mk & 63;
          *(half8*)(kT + (((size_t)b * 8 + hh) * 1088 + n0 + trow) * 128 + dc) = v;
        }
      }
    } else {
      #pragma unroll
      for (int mb = 0; mb < 4; mb++) {
        #pragma unroll
        for (int r = 0; r < 4; r++) {
          int mrow = wm + mb * 16 + lg * 4 + r;
          float bia = qkv_b[m0 + mrow];
          #pragma unroll
          for (int nb = 0; nb < 4; nb++) {
            int tcol = wn + nb * 16 + l15;
            *(_Float16*)(tb + ((mrow * 256 + tcol * 2) ^ ((mrow & 7) << 4))) =
                (_Float16)(acc[mb][nb][r] + bia);
          }
        }
      }
      __syncthreads();
      #pragma unroll
      for (int it = 0; it < 8; it++) {
        int e = it * 256 + tid;
        int mrow = e >> 4, seg = e & 15;
        half8 v = *(const half8*)(tb + ((mrow * 256 + seg * 16) ^ ((mrow & 7) << 4)));
        int mv = m0 - 1024 + mrow, hh = mv >> 6, dc = mv & 63;
        *(half8*)(vT + (((size_t)b * 8 + hh) * 64 + dc) * 1088 + n0 + seg * 8) = v;
      }
    }
  }
}

// proj: A = proj_w f16 (512 x 512), B = attnT (1024 x 512); 128x128 tile, grid (8,4,8)
__global__ __launch_bounds__(256) void k_mfma_proj(
    const _Float16* __restrict__ Abase, const float* __restrict__ bias,
    const _Float16* __restrict__ Ball, const float* __restrict__ xin,
    float* __restrict__ out)
{
  __shared__ _Float16 smem[32768];   // 64KB: A dbuf [0,16384), B dbuf [16384,32768)
  _Float16* ldsA = smem;
  _Float16* ldsB = smem + 16384;
  const int b = blockIdx.z, mt = blockIdx.y, nt = blockIdx.x;
  const int m0 = mt * 128, n0 = nt * 128;
  const _Float16* Bbase = Ball + (size_t)b * 1024 * 512;
  const int tid = threadIdx.x, lane = tid & 63, w = tid >> 6;
  const int l15 = lane & 15, lg = lane >> 4;
  const int wm = (w >> 1) * 64, wn = (w & 1) * 64;
  MFMA_CORE(512)
  #pragma unroll
  for (int mb = 0; mb < 4; mb++) {
    #pragma unroll
    for (int r = 0; r < 4; r++) {
      int m = m0 + wm + mb * 16 + lg * 4 + r;
      float bia = bias[m];
      #pragma unroll
      for (int nb = 0; nb < 4; nb++) {
        int t = n0 + wn + nb * 16 + l15;
        size_t idx = ((size_t)b * NC + m) * NL1 + t;
        out[idx] = xin[idx] + acc[mb][nb][r] + bia;
      }
    }
  }
}

// ====== ipp GN stats + normalize + scatter fused (f16 input) ======
__global__ __launch_bounds__(256) void k_ipp_fuse(
    const _Float16* __restrict__ raw,
    const float* __restrict__ gm, const float* __restrict__ gb,
    _Float16* __restrict__ qT, _Float16* __restrict__ kT)
{
  const int g = blockIdx.x, b = blockIdx.y;
  const int tid = threadIdx.x;
  const _Float16* p = raw + ((size_t)b * 512 + (size_t)g * 16) * 1024;
  const int t0 = tid * 4;

  float4 v[16];
  float s = 0.f, s2 = 0.f;
  #pragma unroll
  for (int c = 0; c < 16; c++) {
    half4 hv = *(const half4*)&p[(size_t)c * 1024 + t0];
    v[c].x = (float)hv.x; v[c].y = (float)hv.y; v[c].z = (float)hv.z; v[c].w = (float)hv.w;
    s += v[c].x + v[c].y + v[c].z + v[c].w;
    s2 += v[c].x * v[c].x + v[c].y * v[c].y + v[c].z * v[c].z + v[c].w * v[c].w;
  }
  #pragma unroll
  for (int o = 32; o > 0; o >>= 1) { s += __shfl_down(s, o); s2 += __shfl_down(s2, o); }
  __shared__ float rs[4], rq[4], stat[2];
  int lane = tid & 63, w = tid >> 6;
  if (lane == 0) { rs[w] = s; rq[w] = s2; }
  __syncthreads();
  if (tid == 0) {
    float S = rs[0] + rs[1] + rs[2] + rs[3];
    float Q = rq[0] + rq[1] + rq[2] + rq[3];
    float mn = S / 16384.f;
    float var = Q / 16384.f - mn * mn;
    if (var < 0.f) var = 0.f;
    stat[0] = mn; stat[1] = rsqrtf(var + EPSV);
  }
  __syncthreads();
  const float mn = stat[0], rstd = stat[1];

  float ga[16], be[16];
  #pragma unroll
  for (int c = 0; c < 16; c++) {
    ga[c] = gm[g * 16 + c] * rstd;
    be[c] = gb[g * 16 + c] - mn * ga[c];
  }

  const size_t bh = (size_t)b * 8 + (g >> 2);
  const int dcb = (g & 3) * 16;
  #pragma unroll
  for (int j = 0; j < 4; j++) {
    const int t = t0 + j;
    half8 k0, k1, q0, q1;
    #pragma unroll
    for (int c = 0; c < 8; c++) {
      float4 vc = v[c];
      float e = (j == 0) ? vc.x : (j == 1) ? vc.y : (j == 2) ? vc.z : vc.w;
      float xn = e * ga[c] + be[c];
      k0[c] = (_Float16)xn;
      q0[c] = (_Float16)(SCALE2Q * xn);
    }
    #pragma unroll
    for (int c = 8; c < 16; c++) {
      float4 vc = v[c];
      float e = (j == 0) ? vc.x : (j == 1) ? vc.y : (j == 2) ? vc.z : vc.w;
      float xn = e * ga[c] + be[c];
      k1[c - 8] = (_Float16)xn;
      q1[c - 8] = (_Float16)(SCALE2Q * xn);
    }
    _Float16* qd = qT + (bh * 1024 + t) * 128 + 64 + dcb;
    _Float16* kd = kT + (bh * 1088 + t) * 128 + 64 + dcb;
    *(half8*)qd = q0; *(half8*)(qd + 8) = q1;
    *(half8*)kd = k0; *(half8*)(kd + 8) = k1;
  }
}

// ====================== fused attention (32x32 swapped, T15 2-deep pipeline) ======================
// Round-4 proven version (54.5 us): K double-buffered, V triple-buffered,
// permlane32_swap builtin for all lane^32 exchanges.
__global__ __launch_bounds__(256, 2) void k_attn_mfma(
    const _Float16* __restrict__ qT, const _Float16* __restrict__ kT,
    const _Float16* __restrict__ vT, const int* __restrict__ mask,
    _Float16* __restrict__ attnT)
{
  const int x = blockIdx.x & 7;
  const int k = blockIdx.x >> 3;
  const int bh = x + ((k >> 3) << 3);
  const int qt = k & 7;
  const int b = bh >> 3, h = bh & 7;
  const int tid = threadIdx.x;
  const int lane = tid & 63;
  const int w = tid >> 6;
  const int l31 = lane & 31;
  const int hi = lane >> 5;

  __shared__ _Float16 KsB[2 * 64 * 128];   // 32KB, 2 buffers of 8192 halfs
  __shared__ _Float16 VtB[3 * 64 * 64];    // 24KB, 3 buffers of 4096 halfs

  const int q = qt * 128 + w * 32 + l31;

  half8 aq[8];
  {
    const _Float16* qp = qT + ((size_t)bh * 1024 + q) * 128 + hi * 8;
    #pragma unroll
    for (int kst = 0; kst < 8; kst++) aq[kst] = *(const half8*)(qp + kst * 16);
  }

  unsigned int mbits = 0;
  {
    const int* mp = mask + b * 64;
    #pragma unroll
    for (int sb = 0; sb < 2; sb++) {
      #pragma unroll
      for (int reg = 0; reg < 16; reg++) {
        int s = sb * 32 + (reg & 3) + 8 * (reg >> 2) + 4 * hi;
        if (mp[s]) mbits |= 1u << (sb * 16 + reg);
      }
    }
  }

  f32x16 O0 = (f32x16)0.f, O1 = (f32x16)0.f;
  f32x16 scA0 = (f32x16)0.f, scA1 = (f32x16)0.f;
  f32x16 scB0 = (f32x16)0.f, scB1 = (f32x16)0.f;
  float m_run = -INFINITY, l_run = 0.f;

  const int kxor = (l31 & 7) << 4;
  const int ksrow_off = lane >> 4;
  const int kcsrc_base = lane & 15;
  const int vdc_off = lane >> 3;
  const int vcsrc_base = lane & 7;

#define STAGE_KV(T, KD, VD)                                                          \
  {                                                                                  \
    const int s0_ = (T) * 64;                                                        \
    _Pragma("unroll") for (int r = 0; r < 4; r++) {                                  \
      int seg = r * 4 + w;                                                           \
      int srow = seg * 4 + ksrow_off;                                                \
      int csrc = kcsrc_base ^ (srow & 7);                                            \
      gload16(kT + ((size_t)bh * 1088 + s0_ + srow) * 128 + csrc * 8, (KD) + seg * 512); \
    }                                                                                \
    _Pragma("unroll") for (int r = 0; r < 2; r++) {                                  \
      int seg = r * 4 + w;                                                           \
      int dc = seg * 8 + vdc_off;                                                    \
      int csrc = vcsrc_base ^ (dc & 7);                                              \
      gload16(vT + ((size_t)bh * 64 + dc) * 1088 + s0_ + csrc * 8, (VD) + seg * 512);  \
    }                                                                                \
  }

// cross-half (lane^32) reduce via permlane32_swap builtin: OUT = OP(x[l], x[l^32])
#define XHALF_FMAX(OUTV, INV)                                                        \
  { unsigned int xi_ = __float_as_uint(INV);                                         \
    uint32x2 xr_ = __builtin_amdgcn_permlane32_swap(xi_, xi_, false, false);         \
    OUTV = fmaxf(__uint_as_float(xr_.x), __uint_as_float(xr_.y)); }
#define XHALF_ADD(OUTV, INV)                                                         \
  { unsigned int xi_ = __float_as_uint(INV);                                         \
    uint32x2 xr_ = __builtin_amdgcn_permlane32_swap(xi_, xi_, false, false);         \
    OUTV = __uint_as_float(xr_.x) + __uint_as_float(xr_.y); }

#define ATTN_ITER(C0, C1, P0, P1, T)                                                 \
  {                                                                                  \
    const int T_ = (T);                                                              \
    if (T_ <= 16) {                                                                  \
      if (T_ <= 15) {                                                                \
        _Float16* kd_ = KsB + (((T_ + 1) & 1) << 13);                                \
        _Float16* vd_ = VtB + ((T_ + 1) % 3) * 4096;                                 \
        STAGE_KV(T_ + 1, kd_, vd_)                                                   \
      }                                                                              \
      const char* ksb_ = (const char*)(KsB + ((T_ & 1) << 13));                      \
      C0 = (f32x16)0.f; C1 = (f32x16)0.f;                                            \
      __builtin_amdgcn_s_setprio(1);                                                 \
      _Pragma("unroll") for (int kst = 0; kst < 8; kst++) {                          \
        half8 kf0 = *(const half8*)(ksb_ + ((l31 * 256 + kst * 32 + hi * 16) ^ kxor)); \
        half8 kf1 = *(const half8*)(ksb_ + (((32 + l31) * 256 + kst * 32 + hi * 16) ^ kxor)); \
        C0 = __builtin_amdgcn_mfma_f32_32x32x16_f16(kf0, aq[kst], C0, 0, 0, 0);      \
        C1 = __builtin_amdgcn_mfma_f32_32x32x16_f16(kf1, aq[kst], C1, 0, 0, 0);      \
      }                                                                              \
      __builtin_amdgcn_s_setprio(0);                                                 \
    }                                                                                \
    if (T_ >= 1) {                                                                   \
      if (T_ == 17) {                                                                \
        _Pragma("unroll") for (int i = 0; i < 16; i++) {                             \
          if ((mbits >> i) & 1)        P0[i] = -INFINITY;                            \
          if ((mbits >> (16 + i)) & 1) P1[i] = -INFINITY;                            \
        }                                                                            \
      }                                                                              \
      float mx;                                                                      \
      {                                                                              \
        float a0 = fmaxf(fmaxf(P0[0], P0[1]), P0[2]);                                \
        float a1 = fmaxf(fmaxf(P0[3], P0[4]), P0[5]);                                \
        float a2 = fmaxf(fmaxf(P0[6], P0[7]), P0[8]);                                \
        float a3 = fmaxf(fmaxf(P0[9], P0[10]), P0[11]);                              \
        float a4 = fmaxf(fmaxf(P0[12], P0[13]), P0[14]);                             \
        float a5 = fmaxf(fmaxf(P0[15], P1[0]), P1[1]);                               \
        float a6 = fmaxf(fmaxf(P1[2], P1[3]), P1[4]);                                \
        float a7 = fmaxf(fmaxf(P1[5], P1[6]), P1[7]);                                \
        float a8 = fmaxf(fmaxf(P1[8], P1[9]), P1[10]);                               \
        float a9 = fmaxf(fmaxf(P1[11], P1[12]), P1[13]);                             \
        float aa = fmaxf(P1[14], P1[15]);                                            \
        float b0 = fmaxf(fmaxf(a0, a1), a2);                                         \
        float b1 = fmaxf(fmaxf(a3, a4), a5);                                         \
        float b2 = fmaxf(fmaxf(a6, a7), a8);                                         \
        float b3 = fmaxf(a9, aa);                                                    \
        mx = fmaxf(fmaxf(b0, b1), fmaxf(b2, b3));                                    \
      }                                                                              \
      XHALF_FMAX(mx, mx)                                                             \
      if (__all(mx <= m_run + DEFER_THR)) {                                          \
        float sum = 0.f;                                                             \
        _Pragma("unroll") for (int i = 0; i < 16; i++) {                             \
          float p = fast_exp2(P0[i] - m_run); P0[i] = p; sum += p; }                 \
        _Pragma("unroll") for (int i = 0; i < 16; i++) {                             \
          float p = fast_exp2(P1[i] - m_run); P1[i] = p; sum += p; }                 \
        XHALF_ADD(sum, sum)                                                          \
        l_run += sum;                                                                \
      } else {                                                                       \
        float m_new = fmaxf(m_run, mx);                                              \
        float alpha = fast_exp2(m_run - m_new);                                      \
        float sum = 0.f;                                                             \
        _Pragma("unroll") for (int i = 0; i < 16; i++) {                             \
          float p = fast_exp2(P0[i] - m_new); P0[i] = p; sum += p; }                 \
        _Pragma("unroll") for (int i = 0; i < 16; i++) {                             \
          float p = fast_exp2(P1[i] - m_new); P1[i] = p; sum += p; }                 \
        XHALF_ADD(sum, sum)                                                          \
        l_run = l_run * alpha + sum;                                                 \
        m_run = m_new;                                                               \
        _Pragma("unroll") for (int i = 0; i < 16; i++) { O0[i] *= alpha; O1[i] *= alpha; } \
      }                                                                              \
      const char* vtb_ = (const char*)(VtB + ((T_ - 1) % 3) * 4096);                 \
      __builtin_amdgcn_s_setprio(1);                                                 \
      _Pragma("unroll") for (int sb = 0; sb < 2; sb++) {                             \
        _Pragma("unroll") for (int k2 = 0; k2 < 2; k2++) {                           \
          const int kst = sb * 2 + k2;                                               \
          unsigned int pa0, pa1, pb0, pb1;                                           \
          if (sb == 0) {                                                             \
            pa0 = pkrtz(P0[8 * k2 + 0], P0[8 * k2 + 1]);                             \
            pa1 = pkrtz(P0[8 * k2 + 2], P0[8 * k2 + 3]);                             \
            pb0 = pkrtz(P0[8 * k2 + 4], P0[8 * k2 + 5]);                             \
            pb1 = pkrtz(P0[8 * k2 + 6], P0[8 * k2 + 7]);                             \
          } else {                                                                   \
            pa0 = pkrtz(P1[8 * k2 + 0], P1[8 * k2 + 1]);                             \
            pa1 = pkrtz(P1[8 * k2 + 2], P1[8 * k2 + 3]);                             \
            pb0 = pkrtz(P1[8 * k2 + 4], P1[8 * k2 + 5]);                             \
            pb1 = pkrtz(P1[8 * k2 + 6], P1[8 * k2 + 7]);                             \
          }                                                                          \
          uint32x2 r0_ = __builtin_amdgcn_permlane32_swap(pa0, pb0, false, false);   \
          uint32x2 r1_ = __builtin_amdgcn_permlane32_swap(pa1, pb1, false, false);   \
          union { unsigned int u[4]; half8 hh; } pf;                                 \
          pf.u[0] = r0_.x;                                                           \
          pf.u[1] = r1_.x;                                                           \
          pf.u[2] = r0_.y;                                                           \
          pf.u[3] = r1_.y;                                                           \
          half8 vf0 = *(const half8*)(vtb_ + ((l31 * 128 + kst * 32 + hi * 16) ^ kxor)); \
          half8 vf1 = *(const half8*)(vtb_ + (((32 + l31) * 128 + kst * 32 + hi * 16) ^ kxor)); \
          O0 = __builtin_amdgcn_mfma_f32_32x32x16_f16(vf0, pf.hh, O0, 0, 0, 0);      \
          O1 = __builtin_amdgcn_mfma_f32_32x32x16_f16(vf1, pf.hh, O1, 0, 0, 0);      \
        }                                                                            \
      }                                                                              \
      __builtin_amdgcn_s_setprio(0);                                                 \
    }                                                                                \
    if (T_ < 17) {                                                                   \
      asm volatile("s_waitcnt vmcnt(0)" ::: "memory");                               \
      __builtin_amdgcn_s_barrier();                                                  \
    }                                                                                \
  }

  STAGE_KV(0, KsB, VtB)
  asm volatile("s_waitcnt vmcnt(0)" ::: "memory");
  __builtin_amdgcn_s_barrier();

  for (int t = 0; t < 18; t += 2) {
    ATTN_ITER(scA0, scA1, scB0, scB1, t)
    ATTN_ITER(scB0, scB1, scA0, scA1, t + 1)
  }

  float inv = 1.f / l_run;
  _Float16* op = attnT + ((size_t)b * 1024 + q) * 512 + h * 64;
  #pragma unroll
  for (int i = 0; i < 16; i += 2) {
    int dc = (i & 3) + 8 * (i >> 2) + 4 * hi;
    unsigned int c0 = pkrtz(O0[i] * inv, O0[i + 1] * inv);
    unsigned int c1 = pkrtz(O1[i] * inv, O1[i + 1] * inv);
    *(unsigned int*)(op + dc) = c0;
    *(unsigned int*)(op + 32 + dc) = c1;
  }
}

// ============================ launcher ============================
extern "C" void kernel_launch(void* const* d_in, const int* in_sizes, int n_in,
                              void* d_out, int out_size, void* d_ws, size_t ws_size,
                              hipStream_t stream) {
  const float* x         = (const float*)d_in[0];
  const float* xf_out    = (const float*)d_in[1];
  const float* obj_class = (const float*)d_in[2];
  const float* obj_bbox  = (const float*)d_in[3];
  const float* ipbe      = (const float*)d_in[4];
  const int*   mask      = (const int*)d_in[5];
  const float* qkv_w     = (const float*)d_in[6];
  const float* qkv_b     = (const float*)d_in[7];
  const float* g_qkv     = (const float*)d_in[8];
  const float* b_qkv     = (const float*)d_in[9];
  const float* lc_w      = (const float*)d_in[10];
  const float* lc_b      = (const float*)d_in[11];
  const float* lp_w      = (const float*)d_in[12];
  const float* lp_b      = (const float*)d_in[13];
  const float* g_obj     = (const float*)d_in[14];
  const float* b_obj     = (const float*)d_in[15];
  const float* g_lpos    = (const float*)d_in[16];
  const float* b_lpos    = (const float*)d_in[17];
  const float* g_ipos    = (const float*)d_in[18];
  const float* b_ipos    = (const float*)d_in[19];
  const float* proj_w    = (const float*)d_in[20];
  const float* proj_b    = (const float*)d_in[21];
  float* out = (float*)d_out;

  _Float16* f16b = (_Float16*)d_ws;
  _Float16* qT      = f16b;                      // 8,388,608
  _Float16* kT      = qT + 8388608;              // 8,912,896
  _Float16* vT      = kT + 8912896;              // 4,456,448
  _Float16* xhatT   = vT + 4456448;              // 4,194,304
  _Float16* ipbeT   = xhatT + 4194304;           // 8,388,608
  _Float16* attnT   = ipbeT + 8388608;           // 4,194,304
  _Float16* w16qkv  = attnT + 4194304;           //   786,432
  _Float16* w16lp   = w16qkv + 786432;           //   524,288
  _Float16* w16proj = w16lp + 524288;            //   262,144
  _Float16* w16lc   = w16proj + 262144;          // 1,048,576
  _Float16* lceT    = w16lc + 1048576;           //   524,288
  _Float16* objT    = lceT + 524288;             //   524,288
  _Float16* ipp16   = objT + 524288;             // 4,194,304
  float* st = (float*)(ipp16 + 4194304);
  float* xm = st, * xr = st + 256, * om = st + 512, * orr = st + 768;

  dim3 blk(256);
  k_init<<<dim3(3072), blk, 0, stream>>>(x, obj_class, xm, xr, om, orr,
                                         qkv_w, w16qkv, lp_w, w16lp, proj_w, w16proj, lc_w, w16lc);
  k_prep<<<dim3(3328), blk, 0, stream>>>(x, xm, xr, g_qkv, b_qkv, xhatT,
                                         ipbe, ipbeT,
                                         xf_out, obj_class, obj_bbox, om, orr, g_obj, b_obj,
                                         lceT, objT);
  k_mfma_big<<<dim3(1120), blk, 0, stream>>>(w16qkv, qkv_b, xhatT,
                                             w16lp, lp_b, ipbeT,
                                             w16lc, lc_b, lceT, objT,
                                             g_lpos, b_lpos,
                                             qT, kT, vT, ipp16);
  k_ipp_fuse<<<dim3(32, 8), blk, 0, stream>>>(ipp16, g_ipos, b_ipos, qT, kT);
  k_attn_mfma<<<dim3(512), blk, 0, stream>>>(qT, kT, vT, mask, attnT);
  k_mfma_proj<<<dim3(8, 4, 8), blk, 0, stream>>>(w16proj, proj_b, attnT, x, out);
}

// Round 9
// 124.949 us; speedup vs baseline: 1.1034x; 1.0026x over previous
//
#include <hip/hip_runtime.h>
#include <math.h>

#define NB 8
#define NC 512
#define NL1 1024
#define NL2 64
#define NLKV 1088
#define NENC 1024
#define EPSV 1e-5f
#define SCALE2 0.08838834764831845f          // 1/sqrt(128)
#define SCALE2Q 0.12752425f                  // SCALE2 * log2(e)
#define DEFER_THR 11.5415603f                // 8 nats in log2 units

typedef _Float16 half8 __attribute__((ext_vector_type(8)));
typedef _Float16 half4 __attribute__((ext_vector_type(4)));
typedef __fp16 fp16x2 __attribute__((ext_vector_type(2)));
typedef float f32x4 __attribute__((ext_vector_type(4)));
typedef float f32x16 __attribute__((ext_vector_type(16)));
typedef unsigned int uint32x2 __attribute__((ext_vector_type(2)));

__device__ __forceinline__ void gload16(const _Float16* g, _Float16* l) {
  __builtin_amdgcn_global_load_lds(
      (const __attribute__((address_space(1))) void*)g,
      (__attribute__((address_space(3))) void*)l, 16, 0, 0);
}

__device__ __forceinline__ unsigned int pkrtz(float a, float b) {
  union { fp16x2 hh; unsigned int uu; } cv;
  cv.hh = __builtin_amdgcn_cvt_pkrtz(a, b);
  return cv.uu;
}

__device__ __forceinline__ float fast_exp2(float x) {
  return __builtin_amdgcn_exp2f(x);
}

// ========== k_init: GN stats (x, obj_class) + all 4 weight converts ==========
__global__ __launch_bounds__(256) void k_init(
    const float* __restrict__ x, const float* __restrict__ obj,
    float* __restrict__ xm, float* __restrict__ xr,
    float* __restrict__ om, float* __restrict__ orr,
    const float* __restrict__ qkv_w, _Float16* __restrict__ w16qkv,
    const float* __restrict__ lp_w, _Float16* __restrict__ w16lp,
    const float* __restrict__ proj_w, _Float16* __restrict__ w16proj,
    const float* __restrict__ lc_w, _Float16* __restrict__ w16lc)
{
  int bid = blockIdx.x;
  if (bid < 512) {
    const float* p; float* meanp; float* rstdp; int n4, n, bg;
    if (bid < 256) {
      bg = bid;
      int b = bg >> 5, g = bg & 31;
      p = x + ((size_t)b * 512 + (size_t)g * 16) * 1024;
      n = 16 * 1024; meanp = xm; rstdp = xr;
    } else {
      bg = bid - 256;
      int b = bg >> 5, g = bg & 31;
      p = obj + ((size_t)b * 1024 + (size_t)g * 32) * 64;
      n = 32 * 64; meanp = om; rstdp = orr;
    }
    n4 = n >> 2;
    float s = 0.f, s2 = 0.f;
    for (int i = threadIdx.x; i < n4; i += 256) {
      float4 v = ((const float4*)p)[i];
      s += v.x + v.y + v.z + v.w;
      s2 += v.x * v.x + v.y * v.y + v.z * v.z + v.w * v.w;
    }
    #pragma unroll
    for (int o = 32; o > 0; o >>= 1) { s += __shfl_down(s, o); s2 += __shfl_down(s2, o); }
    __shared__ float rs[4], rq[4];
    int lane = threadIdx.x & 63, w = threadIdx.x >> 6;
    if (lane == 0) { rs[w] = s; rq[w] = s2; }
    __syncthreads();
    if (threadIdx.x == 0) {
      float S = rs[0] + rs[1] + rs[2] + rs[3];
      float Q = rq[0] + rq[1] + rq[2] + rq[3];
      float m = S / n;
      float v = Q / n - m * m;
      if (v < 0.f) v = 0.f;
      meanp[bg] = m;
      rstdp[bg] = rsqrtf(v + EPSV);
    }
  } else {
    int cb = bid - 512;
    const float* s; _Float16* d; int i4;
    if (cb < 768)        { s = qkv_w;  d = w16qkv;  i4 = cb * 256 + threadIdx.x; }
    else if (cb < 1280)  { s = lp_w;   d = w16lp;   i4 = (cb - 768) * 256 + threadIdx.x; }
    else if (cb < 1536)  { s = proj_w; d = w16proj; i4 = (cb - 1280) * 256 + threadIdx.x; }
    else                 { s = lc_w;   d = w16lc;   i4 = (cb - 1536) * 256 + threadIdx.x; }
    float4 v = *(const float4*)&s[(size_t)i4 * 4];
    half4 o; o.x = (_Float16)v.x; o.y = (_Float16)v.y; o.z = (_Float16)v.z; o.w = (_Float16)v.w;
    *(half4*)&d[(size_t)i4 * 4] = o;
  }
}

// ========== k_prep: gn_xT (1024) + ipbeT (2048) + lceobjT (256) ==========
__global__ __launch_bounds__(256) void k_prep(
    const float* __restrict__ x, const float* __restrict__ xm, const float* __restrict__ xr,
    const float* __restrict__ g_qkv, const float* __restrict__ b_qkv, _Float16* __restrict__ xT,
    const float* __restrict__ ipbe, _Float16* __restrict__ ipbeT,
    const float* __restrict__ xf_out, const float* __restrict__ obj_class,
    const float* __restrict__ obj_bbox,
    const float* __restrict__ om, const float* __restrict__ orr,
    const float* __restrict__ g_obj, const float* __restrict__ b_obj,
    _Float16* __restrict__ lceT, _Float16* __restrict__ objT)
{
  __shared__ _Float16 tile[64][72];
  const int bid = blockIdx.x;
  const int tl = threadIdx.x & 63;
  if (bid < 1024) {
    const int tt = bid & 15, ct = (bid >> 4) & 7, b = bid >> 7;
    const int c0 = ct * 64, t0 = tt * 64;
    const int cp = threadIdx.x >> 6;
    #pragma unroll
    for (int i = 0; i < 16; i++) {
      int c = c0 + i * 4 + cp;
      float v = x[((size_t)b * NC + c) * NL1 + t0 + tl];
      int g = c >> 4;
      float ga = g_qkv[c] * xr[b * 32 + g];
      float be = b_qkv[c] - xm[b * 32 + g] * ga;
      tile[tl][i * 4 + cp] = (_Float16)(v * ga + be);
    }
    __syncthreads();
    int tr = threadIdx.x >> 2, c16 = (threadIdx.x & 3) * 16;
    _Float16* dst = xT + ((size_t)b * 1024 + t0 + tr) * 512 + c0 + c16;
    *(half8*)dst = *(half8*)&tile[tr][c16];
    *(half8*)(dst + 8) = *(half8*)&tile[tr][c16 + 8];
  } else if (bid < 3072) {
    const int e2 = bid - 1024;
    const int tt = e2 & 15, et = (e2 >> 4) & 15, b = e2 >> 8;
    const int e0 = et * 64, t0 = tt * 64;
    const int ep = threadIdx.x >> 6;
    #pragma unroll
    for (int i = 0; i < 16; i++) {
      int e = e0 + i * 4 + ep;
      tile[tl][i * 4 + ep] = (_Float16)ipbe[((size_t)b * 1024 + e) * 1024 + t0 + tl];
    }
    __syncthreads();
    int tr = threadIdx.x >> 2, c16 = (threadIdx.x & 3) * 16;
    _Float16* d = ipbeT + ((size_t)b * 1024 + t0 + tr) * 1024 + e0 + c16;
    *(half8*)d = *(half8*)&tile[tr][c16];
    *(half8*)(d + 8) = *(half8*)&tile[tr][c16 + 8];
  } else {
    const int e2 = bid - 3072;
    const int et = e2 & 15, which = (e2 >> 4) & 1, b = e2 >> 5;
    const int e0 = et * 64;
    const int ep = threadIdx.x >> 6;
    if (which == 0) {
      #pragma unroll
      for (int i = 0; i < 16; i++) {
        int e = e0 + i * 4 + ep;
        size_t idx = ((size_t)b * 1024 + e) * 64 + tl;
        int g = e >> 5;
        float xn = (obj_class[idx] - om[b * 32 + g]) * orr[b * 32 + g] * g_obj[e] + b_obj[e];
        tile[tl][i * 4 + ep] = (_Float16)(0.5f * (xf_out[idx] + xn));
      }
    } else {
      #pragma unroll
      for (int i = 0; i < 16; i++) {
        int e = e0 + i * 4 + ep;
        tile[tl][i * 4 + ep] = (_Float16)obj_bbox[((size_t)b * 1024 + e) * 64 + tl];
      }
    }
    __syncthreads();
    int tr = threadIdx.x >> 2, c16 = (threadIdx.x & 3) * 16;
    _Float16* dst = (which == 0 ? lceT : objT) + ((size_t)b * 64 + tr) * 1024 + e0 + c16;
    *(half8*)dst = *(half8*)&tile[tr][c16];
    *(half8*)(dst + 8) = *(half8*)&tile[tr][c16 + 8];
  }
}

// =================== MFMA GEMM cores (2-phase, counted-vmcnt split barrier) ===================
#define MFMA_CORE(KTOT)                                                                  \
  f32x4 acc[4][4];                                                                       \
  _Pragma("unroll") for (int i_ = 0; i_ < 4; i_++)                                       \
      _Pragma("unroll") for (int j_ = 0; j_ < 4; j_++) acc[i_][j_] = (f32x4)0.f;         \
  {                                                                                      \
    const int rsub = lane >> 3, csrc = (lane & 7) ^ rsub;                                \
    const int NT_ = (KTOT) / 64;                                                         \
    _Pragma("unroll") for (int i = 0; i < 4; i++) {                                      \
      int seg = w * 4 + i;                                                               \
      int row = seg * 8 + rsub;                                                          \
      gload16(Abase + (size_t)(m0 + row) * (KTOT) + csrc * 8, ldsA + seg * 512);         \
      gload16(Bbase + (size_t)(n0 + row) * (KTOT) + csrc * 8, ldsB + seg * 512);         \
    }                                                                                    \
    int cur_ = 0;                                                                        \
    for (int t_ = 0; t_ < NT_; t_++) {                                                   \
      if (t_ + 1 < NT_) {                                                                \
        _Float16* da_ = ldsA + ((cur_ ^ 1) << 13);                                       \
        _Float16* db_ = ldsB + ((cur_ ^ 1) << 13);                                       \
        int kt = (t_ + 1) * 64;                                                          \
        _Pragma("unroll") for (int i = 0; i < 4; i++) {                                  \
          int seg = w * 4 + i;                                                           \
          int row = seg * 8 + rsub;                                                      \
          gload16(Abase + (size_t)(m0 + row) * (KTOT) + kt + csrc * 8, da_ + seg * 512); \
          gload16(Bbase + (size_t)(n0 + row) * (KTOT) + kt + csrc * 8, db_ + seg * 512); \
        }                                                                                \
        asm volatile("s_waitcnt vmcnt(8)" ::: "memory");                                 \
      } else {                                                                           \
        asm volatile("s_waitcnt vmcnt(0)" ::: "memory");                                 \
      }                                                                                  \
      __builtin_amdgcn_s_barrier();                                                      \
      const char* ra_ = (const char*)(ldsA + (cur_ << 13));                              \
      const char* rb_ = (const char*)(ldsB + (cur_ << 13));                              \
      _Pragma("unroll") for (int kk = 0; kk < 2; kk++) {                                 \
        half8 af[4], bf[4];                                                              \
        _Pragma("unroll") for (int mb = 0; mb < 4; mb++) {                               \
          int row = wm + mb * 16 + l15;                                                  \
          af[mb] = *(const half8*)(ra_ + row * 128 +                                     \
                                   ((kk * 64 + lg * 16) ^ ((row & 7) << 4)));            \
        }                                                                                \
        _Pragma("unroll") for (int nb = 0; nb < 4; nb++) {                               \
          int row = wn + nb * 16 + l15;                                                  \
          bf[nb] = *(const half8*)(rb_ + row * 128 +                                     \
                                   ((kk * 64 + lg * 16) ^ ((row & 7) << 4)));            \
        }                                                                                \
        _Pragma("unroll") for (int mb = 0; mb < 4; mb++)                                 \
            _Pragma("unroll") for (int nb = 0; nb < 4; nb++)                             \
                acc[mb][nb] = __builtin_amdgcn_mfma_f32_16x16x32_f16(af[mb], bf[nb],     \
                                                                    acc[mb][nb], 0, 0, 0);\
      }                                                                                  \
      __builtin_amdgcn_s_barrier();                                                      \
      cur_ ^= 1;                                                                         \
    }                                                                                    \
  }

#define MFMA_CORE_N64(KTOT)                                                              \
  f32x4 acc[4][2];                                                                       \
  _Pragma("unroll") for (int i_ = 0; i_ < 4; i_++)                                       \
      _Pragma("unroll") for (int j_ = 0; j_ < 2; j_++) acc[i_][j_] = (f32x4)0.f;         \
  {                                                                                      \
    const int rsub = lane >> 3, csrc = (lane & 7) ^ rsub;                                \
    const int NT_ = (KTOT) / 64;                                                         \
    _Pragma("unroll") for (int i = 0; i < 4; i++) {                                      \
      int seg = w * 4 + i;                                                               \
      int row = seg * 8 + rsub;                                                          \
      gload16(Abase + (size_t)(m0 + row) * (KTOT) + csrc * 8, ldsA + seg * 512);         \
    }                                                                                    \
    _Pragma("unroll") for (int i = 0; i < 2; i++) {                                      \
      int seg = w * 2 + i;                                                               \
      int row = seg * 8 + rsub;                                                          \
      gload16(Bbase + (size_t)row * (KTOT) + csrc * 8, ldsB + seg * 512);                \
    }                                                                                    \
    int cur_ = 0;                                                                        \
    for (int t_ = 0; t_ < NT_; t_++) {                                                   \
      if (t_ + 1 < NT_) {                                                                \
        _Float16* da_ = ldsA + ((cur_ ^ 1) << 13);                                       \
        _Float16* db_ = ldsB + ((cur_ ^ 1) << 12);                                       \
        int kt = (t_ + 1) * 64;                                                          \
        _Pragma("unroll") for (int i = 0; i < 4; i++) {                                  \
          int seg = w * 4 + i;                                                           \
          int row = seg * 8 + rsub;                                                      \
          gload16(Abase + (size_t)(m0 + row) * (KTOT) + kt + csrc * 8, da_ + seg * 512); \
        }                                                                                \
        _Pragma("unroll") for (int i = 0; i < 2; i++) {                                  \
          int seg = w * 2 + i;                                                           \
          int row = seg * 8 + rsub;                                                      \
          gload16(Bbase + (size_t)row * (KTOT) + kt + csrc * 8, db_ + seg * 512);        \
        }                                                                                \
        asm volatile("s_waitcnt vmcnt(6)" ::: "memory");                                 \
      } else {                                                                           \
        asm volatile("s_waitcnt vmcnt(0)" ::: "memory");                                 \
      }                                                                                  \
      __builtin_amdgcn_s_barrier();                                                      \
      const char* ra_ = (const char*)(ldsA + (cur_ << 13));                              \
      const char* rb_ = (const char*)(ldsB + (cur_ << 12));                              \
      _Pragma("unroll") for (int kk = 0; kk < 2; kk++) {                                 \
        half8 af[4], bf[2];                                                              \
        _Pragma("unroll") for (int mb = 0; mb < 4; mb++) {                               \
          int row = wm + mb * 16 + l15;                                                  \
          af[mb] = *(const half8*)(ra_ + row * 128 +                                     \
                                   ((kk * 64 + lg * 16) ^ ((row & 7) << 4)));            \
        }                                                                                \
        _Pragma("unroll") for (int nb = 0; nb < 2; nb++) {                               \
          int row = wn + nb * 16 + l15;                                                  \
          bf[nb] = *(const half8*)(rb_ + row * 128 +                                     \
                                   ((kk * 64 + lg * 16) ^ ((row & 7) << 4)));            \
        }                                                                                \
        _Pragma("unroll") for (int mb = 0; mb < 4; mb++)                                 \
            _Pragma("unroll") for (int nb = 0; nb < 2; nb++)                             \
                acc[mb][nb] = __builtin_amdgcn_mfma_f32_16x16x32_f16(af[mb], bf[nb],     \
                                                                    acc[mb][nb], 0, 0, 0);\
      }                                                                                  \
      __builtin_amdgcn_s_barrier();                                                      \
      cur_ ^= 1;                                                                         \
    }                                                                                    \
  }

// ====== k_mfma_big: ipp [0,256) + lc/lpe [256,352) + qkv [352,1120) ======
__global__ __launch_bounds__(256) void k_mfma_big(
    const _Float16* __restrict__ w16qkv, const float* __restrict__ qkv_b,
    const _Float16* __restrict__ xhatT,
    const _Float16* __restrict__ w16lp, const float* __restrict__ lp_b,
    const _Float16* __restrict__ ipbeT,
    const _Float16* __restrict__ w16lc, const float* __restrict__ lc_b,
    const _Float16* __restrict__ lceT, const _Float16* __restrict__ objT,
    const float* __restrict__ g_lpos, const float* __restrict__ b_lpos,
    _Float16* __restrict__ qT, _Float16* __restrict__ kT, _Float16* __restrict__ vT,
    _Float16* __restrict__ ipp16)
{
  __shared__ _Float16 smem[32768];   // 64KB: A dbuf [0,16384), B dbuf [16384,32768)
  const int bid0 = blockIdx.x;
  const int tid = threadIdx.x, lane = tid & 63, w = tid >> 6;
  const int l15 = lane & 15, lg = lane >> 4;

  if (bid0 < 256) {
    // ---- ipp: A = lp_w (512 x 1024), B = ipbeT, tile 128x128 ----
    const int nt = bid0 & 7, mt = (bid0 >> 3) & 3, b = bid0 >> 5;
    const int m0 = mt * 128, n0 = nt * 128;
    _Float16* ldsA = smem;
    _Float16* ldsB = smem + 16384;
    const _Float16* Abase = w16lp;
    const _Float16* Bbase = ipbeT + (size_t)b * 1024 * 1024;
    const int wm = (w >> 1) * 64, wn = (w & 1) * 64;
    MFMA_CORE(1024)
    #pragma unroll
    for (int mb = 0; mb < 4; mb++) {
      #pragma unroll
      for (int r = 0; r < 4; r++) {
        int m = m0 + wm + mb * 16 + lg * 4 + r;
        float bia = lp_b[m];
        #pragma unroll
        for (int nb = 0; nb < 4; nb++) {
          int t = n0 + wn + nb * 16 + l15;
          ipp16[((size_t)b * NC + m) * NL1 + t] = (_Float16)(acc[mb][nb][r] + bia);
        }
      }
    }
  } else if (bid0 < 352) {
    // ---- lc/lpe: tile 128x64, K=1024; lpe fuses GroupNorm ----
    const int local = bid0 - 256;
    const int mt = local % 12, b = local / 12;
    const bool islc = (mt < 8);
    const int m0 = (islc ? mt : mt - 8) * 128;
    _Float16* ldsA = smem;
    _Float16* ldsB = smem + 16384;
    float (*red_s)[4] = (float(*)[4])(smem + 24576);
    float (*red_q)[4] = (float(*)[4])(smem + 24608);
    const _Float16* Abase = islc ? w16lc : w16lp;
    const float* bias = islc ? lc_b : lp_b;
    const _Float16* Bbase = (islc ? lceT : objT) + (size_t)b * 64 * 1024;
    const int wm = (w >> 1) * 64, wn = (w & 1) * 32;
    MFMA_CORE_N64(1024)

    if (islc) {
      #pragma unroll
      for (int mb = 0; mb < 4; mb++) {
        #pragma unroll
        for (int r = 0; r < 4; r++) {
          int m = m0 + wm + mb * 16 + lg * 4 + r;
          float bia = bias[m];
          #pragma unroll
          for (int nb = 0; nb < 2; nb++) {
            int l = wn + nb * 16 + l15;
            float val = acc[mb][nb][r] + bia;
            if (m < 512) {
              int h = m >> 6, dc = m & 63;
              kT[(((size_t)b * 8 + h) * 1088 + 1024 + l) * 128 + dc] = (_Float16)val;
            } else {
              int mv = m - 512, h = mv >> 6, dc = mv & 63;
              vT[(((size_t)b * 8 + h) * 64 + dc) * 1088 + 1024 + l] = (_Float16)val;
            }
          }
        }
      }
    } else {
      float vals[4][2][4];
      float ps[4], pq[4];
      #pragma unroll
      for (int mb = 0; mb < 4; mb++) {
        ps[mb] = 0.f; pq[mb] = 0.f;
        #pragma unroll
        for (int r = 0; r < 4; r++) {
          int m = m0 + wm + mb * 16 + lg * 4 + r;
          float bia = bias[m];
          #pragma unroll
          for (int nb = 0; nb < 2; nb++) {
            float val = acc[mb][nb][r] + bia;
            vals[mb][nb][r] = val;
            ps[mb] += val; pq[mb] += val * val;
          }
        }
      }
      #pragma unroll
      for (int mb = 0; mb < 4; mb++) {
        #pragma unroll
        for (int o = 32; o > 0; o >>= 1) {
          ps[mb] += __shfl_xor(ps[mb], o);
          pq[mb] += __shfl_xor(pq[mb], o);
        }
      }
      if (lane == 0) {
        #pragma unroll
        for (int mb = 0; mb < 4; mb++) { red_s[w][mb] = ps[mb]; red_q[w][mb] = pq[mb]; }
      }
      __syncthreads();
      const int wbase = (wm >> 6) * 2;
      #pragma unroll
      for (int mb = 0; mb < 4; mb++) {
        float S = red_s[wbase][mb] + red_s[wbase + 1][mb];
        float Q = red_q[wbase][mb] + red_q[wbase + 1][mb];
        float mean = S * (1.f / 1024.f);
        float var = Q * (1.f / 1024.f) - mean * mean;
        if (var < 0.f) var = 0.f;
        float rstd = rsqrtf(var + EPSV);
        #pragma unroll
        for (int r = 0; r < 4; r++) {
          int c = m0 + wm + mb * 16 + lg * 4 + r;
          float ga = g_lpos[c] * rstd;
          float be = b_lpos[c] - mean * ga;
          int hh = c >> 6, dc = c & 63;
          #pragma unroll
          for (int nb = 0; nb < 2; nb++) {
            int l = wn + nb * 16 + l15;
            float xn = vals[mb][nb][r] * ga + be;
            kT[(((size_t)b * 8 + hh) * 1088 + 1024 + l) * 128 + 64 + dc] = (_Float16)xn;
          }
        }
      }
    }
  } else {
    // ---- qkv: A = qkv_w (1536 x 512), B = xhatT (1024 x 512), tile 128x128 ----
    const int bid = bid0 - 352;
    const int nt = bid & 7, tt = bid >> 3;
    const int mt = tt % 12, b = tt / 12;
    const int m0 = mt * 128, n0 = nt * 128;
    _Float16* ldsA = smem;
    _Float16* ldsB = smem + 16384;
    const _Float16* Abase = w16qkv;
    const _Float16* Bbase = xhatT + (size_t)b * 1024 * 512;
    const int wm = (w >> 1) * 64, wn = (w & 1) * 64;
    MFMA_CORE(512)

    char* tb = (char*)smem;
    if (m0 < 1024) {
      const bool isq = (m0 < 512);
      const float qs = isq ? SCALE2Q : 1.f;
      #pragma unroll
      for (int mb = 0; mb < 4; mb++) {
        #pragma unroll
        for (int r = 0; r < 4; r++) {
          int mcol = wm + mb * 16 + lg * 4 + r;
          float bia = qkv_b[m0 + mcol];
          #pragma unroll
          for (int nb = 0; nb < 4; nb++) {
            int trow = wn + nb * 16 + l15;
            float val = (acc[mb][nb][r] + bia) * qs;
            *(_Float16*)(tb + ((trow * 256 + mcol * 2) ^ ((trow & 7) << 4))) = (_Float16)val;
          }
        }
      }
      __syncthreads();
      #pragma unroll
      for (int it = 0; it < 8; it++) {
        int e = it * 256 + tid;
        int trow = e >> 4, seg = e & 15;
        half8 v = *(const half8*)(tb + ((trow * 256 + seg * 16) ^ ((trow & 7) << 4)));
        if (isq) {
          int mq = m0 + seg * 8, hh = mq >> 6, dc = mq & 63;
          *(half8*)(qT + (((size_t)b * 8 + hh) * 1024 + n0 + trow) * 128 + dc) = v;
        } else {
          int mk = m0 - 512 + seg * 8, hh = mk >> 6, dc = mk & 63;
          *(half8*)(kT + (((size_t)b * 8 + hh) * 1088 + n0 + trow) * 128 + dc) = v;
        }
      }
    } else {
      #pragma unroll
      for (int mb = 0; mb < 4; mb++) {
        #pragma unroll
        for (int r = 0; r < 4; r++) {
          int mrow = wm + mb * 16 + lg * 4 + r;
          float bia = qkv_b[m0 + mrow];
          #pragma unroll
          for (int nb = 0; nb < 4; nb++) {
            int tcol = wn + nb * 16 + l15;
            *(_Float16*)(tb + ((mrow * 256 + tcol * 2) ^ ((mrow & 7) << 4))) =
                (_Float16)(acc[mb][nb][r] + bia);
          }
        }
      }
      __syncthreads();
      #pragma unroll
      for (int it = 0; it < 8; it++) {
        int e = it * 256 + tid;
        int mrow = e >> 4, seg = e & 15;
        half8 v = *(const half8*)(tb + ((mrow * 256 + seg * 16) ^ ((mrow & 7) << 4)));
        int mv = m0 - 1024 + mrow, hh = mv >> 6, dc = mv & 63;
        *(half8*)(vT + (((size_t)b * 8 + hh) * 64 + dc) * 1088 + n0 + seg * 8) = v;
      }
    }
  }
}

// proj: A = proj_w f16 (512 x 512), B = attnT (1024 x 512); 128x128 tile, grid (8,4,8)
__global__ __launch_bounds__(256) void k_mfma_proj(
    const _Float16* __restrict__ Abase, const float* __restrict__ bias,
    const _Float16* __restrict__ Ball, const float* __restrict__ xin,
    float* __restrict__ out)
{
  __shared__ _Float16 smem[32768];   // 64KB: A dbuf [0,16384), B dbuf [16384,32768)
  _Float16* ldsA = smem;
  _Float16* ldsB = smem + 16384;
  const int b = blockIdx.z, mt = blockIdx.y, nt = blockIdx.x;
  const int m0 = mt * 128, n0 = nt * 128;
  const _Float16* Bbase = Ball + (size_t)b * 1024 * 512;
  const int tid = threadIdx.x, lane = tid & 63, w = tid >> 6;
  const int l15 = lane & 15, lg = lane >> 4;
  const int wm = (w >> 1) * 64, wn = (w & 1) * 64;
  MFMA_CORE(512)
  #pragma unroll
  for (int mb = 0; mb < 4; mb++) {
    #pragma unroll
    for (int r = 0; r < 4; r++) {
      int m = m0 + wm + mb * 16 + lg * 4 + r;
      float bia = bias[m];
      #pragma unroll
      for (int nb = 0; nb < 4; nb++) {
        int t = n0 + wn + nb * 16 + l15;
        size_t idx = ((size_t)b * NC + m) * NL1 + t;
        out[idx] = xin[idx] + acc[mb][nb][r] + bia;
      }
    }
  }
}

// ====== ipp GN stats + normalize + scatter fused (f16 input) ======
__global__ __launch_bounds__(256) void k_ipp_fuse(
    const _Float16* __restrict__ raw,
    const float* __restrict__ gm, const float* __restrict__ gb,
    _Float16* __restrict__ qT, _Float16* __restrict__ kT)
{
  const int g = blockIdx.x, b = blockIdx.y;
  const int tid = threadIdx.x;
  const _Float16* p = raw + ((size_t)b * 512 + (size_t)g * 16) * 1024;
  const int t0 = tid * 4;

  float4 v[16];
  float s = 0.f, s2 = 0.f;
  #pragma unroll
  for (int c = 0; c < 16; c++) {
    half4 hv = *(const half4*)&p[(size_t)c * 1024 + t0];
    v[c].x = (float)hv.x; v[c].y = (float)hv.y; v[c].z = (float)hv.z; v[c].w = (float)hv.w;
    s += v[c].x + v[c].y + v[c].z + v[c].w;
    s2 += v[c].x * v[c].x + v[c].y * v[c].y + v[c].z * v[c].z + v[c].w * v[c].w;
  }
  #pragma unroll
  for (int o = 32; o > 0; o >>= 1) { s += __shfl_down(s, o); s2 += __shfl_down(s2, o); }
  __shared__ float rs[4], rq[4], stat[2];
  int lane = tid & 63, w = tid >> 6;
  if (lane == 0) { rs[w] = s; rq[w] = s2; }
  __syncthreads();
  if (tid == 0) {
    float S = rs[0] + rs[1] + rs[2] + rs[3];
    float Q = rq[0] + rq[1] + rq[2] + rq[3];
    float mn = S / 16384.f;
    float var = Q / 16384.f - mn * mn;
    if (var < 0.f) var = 0.f;
    stat[0] = mn; stat[1] = rsqrtf(var + EPSV);
  }
  __syncthreads();
  const float mn = stat[0], rstd = stat[1];

  float ga[16], be[16];
  #pragma unroll
  for (int c = 0; c < 16; c++) {
    ga[c] = gm[g * 16 + c] * rstd;
    be[c] = gb[g * 16 + c] - mn * ga[c];
  }

  const size_t bh = (size_t)b * 8 + (g >> 2);
  const int dcb = (g & 3) * 16;
  #pragma unroll
  for (int j = 0; j < 4; j++) {
    const int t = t0 + j;
    half8 k0, k1, q0, q1;
    #pragma unroll
    for (int c = 0; c < 8; c++) {
      float4 vc = v[c];
      float e = (j == 0) ? vc.x : (j == 1) ? vc.y : (j == 2) ? vc.z : vc.w;
      float xn = e * ga[c] + be[c];
      k0[c] = (_Float16)xn;
      q0[c] = (_Float16)(SCALE2Q * xn);
    }
    #pragma unroll
    for (int c = 8; c < 16; c++) {
      float4 vc = v[c];
      float e = (j == 0) ? vc.x : (j == 1) ? vc.y : (j == 2) ? vc.z : vc.w;
      float xn = e * ga[c] + be[c];
      k1[c - 8] = (_Float16)xn;
      q1[c - 8] = (_Float16)(SCALE2Q * xn);
    }
    _Float16* qd = qT + (bh * 1024 + t) * 128 + 64 + dcb;
    _Float16* kd = kT + (bh * 1088 + t) * 128 + 64 + dcb;
    *(half8*)qd = q0; *(half8*)(qd + 8) = q1;
    *(half8*)kd = k0; *(half8*)(kd + 8) = k1;
  }
}

// ====================== fused attention (32x32 swapped, T15, 8-wave blocks) ======================
// Round 9: block = 512 threads = 8 waves, each wave keeps the proven 32-Q-row structure.
// One block stages the 24KB K/V tile per iter for 8 waves (was: per 4) -> per-CU L2
// staging traffic halves. Grid 256 (1 block/CU); bh in LOW bits of bid so the 4
// qt-blocks of a bh (bid, bid+64, bid+128, bid+192) share an XCD -> K/V L2-resident.
__global__ __launch_bounds__(512, 1) void k_attn_mfma(
    const _Float16* __restrict__ qT, const _Float16* __restrict__ kT,
    const _Float16* __restrict__ vT, const int* __restrict__ mask,
    _Float16* __restrict__ attnT)
{
  const int bid = blockIdx.x;
  const int bh = bid & 63;
  const int qt = bid >> 6;
  const int b = bh >> 3, h = bh & 7;
  const int tid = threadIdx.x;
  const int lane = tid & 63;
  const int w = tid >> 6;          // 0..7
  const int l31 = lane & 31;
  const int hi = lane >> 5;

  __shared__ _Float16 KsB[2 * 64 * 128];   // 32KB, 2 buffers of 8192 halfs
  __shared__ _Float16 VtB[3 * 64 * 64];    // 24KB, 3 buffers of 4096 halfs

  const int q = qt * 256 + w * 32 + l31;

  half8 aq[8];
  {
    const _Float16* qp = qT + ((size_t)bh * 1024 + q) * 128 + hi * 8;
    #pragma unroll
    for (int kst = 0; kst < 8; kst++) aq[kst] = *(const half8*)(qp + kst * 16);
  }

  unsigned int mbits = 0;
  {
    const int* mp = mask + b * 64;
    #pragma unroll
    for (int sb = 0; sb < 2; sb++) {
      #pragma unroll
      for (int reg = 0; reg < 16; reg++) {
        int s = sb * 32 + (reg & 3) + 8 * (reg >> 2) + 4 * hi;
        if (mp[s]) mbits |= 1u << (sb * 16 + reg);
      }
    }
  }

  f32x16 O0 = (f32x16)0.f, O1 = (f32x16)0.f;
  f32x16 scA0 = (f32x16)0.f, scA1 = (f32x16)0.f;
  f32x16 scB0 = (f32x16)0.f, scB1 = (f32x16)0.f;
  float m_run = -INFINITY, l_run = 0.f;

  const int kxor = (l31 & 7) << 4;
  const int ksrow_off = lane >> 4;
  const int kcsrc_base = lane & 15;
  const int vdc_off = lane >> 3;
  const int vcsrc_base = lane & 7;

// 8 waves share staging: K = 16 segs (2/wave), V = 8 segs (1/wave); 3 gload16/wave.
#define STAGE_KV(T, KD, VD)                                                          \
  {                                                                                  \
    const int s0_ = (T) * 64;                                                        \
    _Pragma("unroll") for (int r = 0; r < 2; r++) {                                  \
      int seg = r * 8 + w;                                                           \
      int srow = seg * 4 + ksrow_off;                                                \
      int csrc = kcsrc_base ^ (srow & 7);                                            \
      gload16(kT + ((size_t)bh * 1088 + s0_ + srow) * 128 + csrc * 8, (KD) + seg * 512); \
    }                                                                                \
    {                                                                                \
      int seg = w;                                                                   \
      int dc = seg * 8 + vdc_off;                                                    \
      int csrc = vcsrc_base ^ (dc & 7);                                              \
      gload16(vT + ((size_t)bh * 64 + dc) * 1088 + s0_ + csrc * 8, (VD) + seg * 512);  \
    }                                                                                \
  }

// cross-half (lane^32) reduce via permlane32_swap builtin: OUT = OP(x[l], x[l^32])
#define XHALF_FMAX(OUTV, INV)                                                        \
  { unsigned int xi_ = __float_as_uint(INV);                                         \
    uint32x2 xr_ = __builtin_amdgcn_permlane32_swap(xi_, xi_, false, false);         \
    OUTV = fmaxf(__uint_as_float(xr_.x), __uint_as_float(xr_.y)); }
#define XHALF_ADD(OUTV, INV)                                                         \
  { unsigned int xi_ = __float_as_uint(INV);                                         \
    uint32x2 xr_ = __builtin_amdgcn_permlane32_swap(xi_, xi_, false, false);         \
    OUTV = __uint_as_float(xr_.x) + __uint_as_float(xr_.y); }

#define ATTN_ITER(C0, C1, P0, P1, T)                                                 \
  {                                                                                  \
    const int T_ = (T);                                                              \
    if (T_ <= 16) {                                                                  \
      if (T_ <= 15) {                                                                \
        _Float16* kd_ = KsB + (((T_ + 1) & 1) << 13);                                \
        _Float16* vd_ = VtB + ((T_ + 1) % 3) * 4096;                                 \
        STAGE_KV(T_ + 1, kd_, vd_)                                                   \
      }                                                                              \
      const char* ksb_ = (const char*)(KsB + ((T_ & 1) << 13));                      \
      C0 = (f32x16)0.f; C1 = (f32x16)0.f;                                            \
      __builtin_amdgcn_s_setprio(1);                                                 \
      _Pragma("unroll") for (int kst = 0; kst < 8; kst++) {                          \
        half8 kf0 = *(const half8*)(ksb_ + ((l31 * 256 + kst * 32 + hi * 16) ^ kxor)); \
        half8 kf1 = *(const half8*)(ksb_ + (((32 + l31) * 256 + kst * 32 + hi * 16) ^ kxor)); \
        C0 = __builtin_amdgcn_mfma_f32_32x32x16_f16(kf0, aq[kst], C0, 0, 0, 0);      \
        C1 = __builtin_amdgcn_mfma_f32_32x32x16_f16(kf1, aq[kst], C1, 0, 0, 0);      \
      }                                                                              \
      __builtin_amdgcn_s_setprio(0);                                                 \
    }                                                                                \
    if (T_ >= 1) {                                                                   \
      if (T_ == 17) {                                                                \
        _Pragma("unroll") for (int i = 0; i < 16; i++) {                             \
          if ((mbits >> i) & 1)        P0[i] = -INFINITY;                            \
          if ((mbits >> (16 + i)) & 1) P1[i] = -INFINITY;                            \
        }                                                                            \
      }                                                                              \
      float mx;                                                                      \
      {                                                                              \
        float a0 = fmaxf(fmaxf(P0[0], P0[1]), P0[2]);                                \
        float a1 = fmaxf(fmaxf(P0[3], P0[4]), P0[5]);                                \
        float a2 = fmaxf(fmaxf(P0[6], P0[7]), P0[8]);                                \
        float a3 = fmaxf(fmaxf(P0[9], P0[10]), P0[11]);                              \
        float a4 = fmaxf(fmaxf(P0[12], P0[13]), P0[14]);                             \
        float a5 = fmaxf(fmaxf(P0[15], P1[0]), P1[1]);                               \
        float a6 = fmaxf(fmaxf(P1[2], P1[3]), P1[4]);                                \
        float a7 = fmaxf(fmaxf(P1[5], P1[6]), P1[7]);                                \
        float a8 = fmaxf(fmaxf(P1[8], P1[9]), P1[10]);                               \
        float a9 = fmaxf(fmaxf(P1[11], P1[12]), P1[13]);                             \
        float aa = fmaxf(P1[14], P1[15]);                                            \
        float b0 = fmaxf(fmaxf(a0, a1), a2);                                         \
        float b1 = fmaxf(fmaxf(a3, a4), a5);                                         \
        float b2 = fmaxf(fmaxf(a6, a7), a8);                                         \
        float b3 = fmaxf(a9, aa);                                                    \
        mx = fmaxf(fmaxf(b0, b1), fmaxf(b2, b3));                                    \
      }                                                                              \
      XHALF_FMAX(mx, mx)                                                             \
      if (__all(mx <= m_run + DEFER_THR)) {                                          \
        float sum = 0.f;                                                             \
        _Pragma("unroll") for (int i = 0; i < 16; i++) {                             \
          float p = fast_exp2(P0[i] - m_run); P0[i] = p; sum += p; }                 \
        _Pragma("unroll") for (int i = 0; i < 16; i++) {                             \
          float p = fast_exp2(P1[i] - m_run); P1[i] = p; sum += p; }                 \
        XHALF_ADD(sum, sum)                                                          \
        l_run += sum;                                                                \
      } else {                                                                       \
        float m_new = fmaxf(m_run, mx);                                              \
        float alpha = fast_exp2(m_run - m_new);                                      \
        float sum = 0.f;                                                             \
        _Pragma("unroll") for (int i = 0; i < 16; i++) {                             \
          float p = fast_exp2(P0[i] - m_new); P0[i] = p; sum += p; }                 \
        _Pragma("unroll") for (int i = 0; i < 16; i++) {                             \
          float p = fast_exp2(P1[i] - m_new); P1[i] = p; sum += p; }                 \
        XHALF_ADD(sum, sum)                                                          \
        l_run = l_run * alpha + sum;                                                 \
        m_run = m_new;                                                               \
        _Pragma("unroll") for (int i = 0; i < 16; i++) { O0[i] *= alpha; O1[i] *= alpha; } \
      }                                                                              \
      const char* vtb_ = (const char*)(VtB + ((T_ - 1) % 3) * 4096);                 \
      __builtin_amdgcn_s_setprio(1);                                                 \
      _Pragma("unroll") for (int sb = 0; sb < 2; sb++) {                             \
        _Pragma("unroll") for (int k2 = 0; k2 < 2; k2++) {                           \
          const int kst = sb * 2 + k2;                                               \
          unsigned int pa0, pa1, pb0, pb1;                                           \
          if (sb == 0) {                                                             \
            pa0 = pkrtz(P0[8 * k2 + 0], P0[8 * k2 + 1]);                             \
            pa1 = pkrtz(P0[8 * k2 + 2], P0[8 * k2 + 3]);                             \
            pb0 = pkrtz(P0[8 * k2 + 4], P0[8 * k2 + 5]);                             \
            pb1 = pkrtz(P0[8 * k2 + 6], P0[8 * k2 + 7]);                             \
          } else {                                                                   \
            pa0 = pkrtz(P1[8 * k2 + 0], P1[8 * k2 + 1]);                             \
            pa1 = pkrtz(P1[8 * k2 + 2], P1[8 * k2 + 3]);                             \
            pb0 = pkrtz(P1[8 * k2 + 4], P1[8 * k2 + 5]);                             \
            pb1 = pkrtz(P1[8 * k2 + 6], P1[8 * k2 + 7]);                             \
          }                                                                          \
          uint32x2 r0_ = __builtin_amdgcn_permlane32_swap(pa0, pb0, false, false);   \
          uint32x2 r1_ = __builtin_amdgcn_permlane32_swap(pa1, pb1, false, false);   \
          union { unsigned int u[4]; half8 hh; } pf;                                 \
          pf.u[0] = r0_.x;                                                           \
          pf.u[1] = r1_.x;                                                           \
          pf.u[2] = r0_.y;                                                           \
          pf.u[3] = r1_.y;                                                           \
          half8 vf0 = *(const half8*)(vtb_ + ((l31 * 128 + kst * 32 + hi * 16) ^ kxor)); \
          half8 vf1 = *(const half8*)(vtb_ + (((32 + l31) * 128 + kst * 32 + hi * 16) ^ kxor)); \
          O0 = __builtin_amdgcn_mfma_f32_32x32x16_f16(vf0, pf.hh, O0, 0, 0, 0);      \
          O1 = __builtin_amdgcn_mfma_f32_32x32x16_f16(vf1, pf.hh, O1, 0, 0, 0);      \
        }                                                                            \
      }                                                                              \
      __builtin_amdgcn_s_setprio(0);                                                 \
    }                                                                                \
    if (T_ < 17) {                                                                   \
      asm volatile("s_waitcnt vmcnt(0)" ::: "memory");                               \
      __builtin_amdgcn_s_barrier();                                                  \
    }                                                                                \
  }

  STAGE_KV(0, KsB, VtB)
  asm volatile("s_waitcnt vmcnt(0)" ::: "memory");
  __builtin_amdgcn_s_barrier();

  for (int t = 0; t < 18; t += 2) {
    ATTN_ITER(scA0, scA1, scB0, scB1, t)
    ATTN_ITER(scB0, scB1, scA0, scA1, t + 1)
  }

  float inv = 1.f / l_run;
  _Float16* op = attnT + ((size_t)b * 1024 + q) * 512 + h * 64;
  #pragma unroll
  for (int i = 0; i < 16; i += 2) {
    int dc = (i & 3) + 8 * (i >> 2) + 4 * hi;
    unsigned int c0 = pkrtz(O0[i] * inv, O0[i + 1] * inv);
    unsigned int c1 = pkrtz(O1[i] * inv, O1[i + 1] * inv);
    *(unsigned int*)(op + dc) = c0;
    *(unsigned int*)(op + 32 + dc) = c1;
  }
}

// ============================ launcher ============================
extern "C" void kernel_launch(void* const* d_in, const int* in_sizes, int n_in,
                              void* d_out, int out_size, void* d_ws, size_t ws_size,
                              hipStream_t stream) {
  const float* x         = (const float*)d_in[0];
  const float* xf_out    = (const float*)d_in[1];
  const float* obj_class = (const float*)d_in[2];
  const float* obj_bbox  = (const float*)d_in[3];
  const float* ipbe      = (const float*)d_in[4];
  const int*   mask      = (const int*)d_in[5];
  const float* qkv_w     = (const float*)d_in[6];
  const float* qkv_b     = (const float*)d_in[7];
  const float* g_qkv     = (const float*)d_in[8];
  const float* b_qkv     = (const float*)d_in[9];
  const float* lc_w      = (const float*)d_in[10];
  const float* lc_b      = (const float*)d_in[11];
  const float* lp_w      = (const float*)d_in[12];
  const float* lp_b      = (const float*)d_in[13];
  const float* g_obj     = (const float*)d_in[14];
  const float* b_obj     = (const float*)d_in[15];
  const float* g_lpos    = (const float*)d_in[16];
  const float* b_lpos    = (const float*)d_in[17];
  const float* g_ipos    = (const float*)d_in[18];
  const float* b_ipos    = (const float*)d_in[19];
  const float* proj_w    = (const float*)d_in[20];
  const float* proj_b    = (const float*)d_in[21];
  float* out = (float*)d_out;

  _Float16* f16b = (_Float16*)d_ws;
  _Float16* qT      = f16b;                      // 8,388,608
  _Float16* kT      = qT + 8388608;              // 8,912,896
  _Float16* vT      = kT + 8912896;              // 4,456,448
  _Float16* xhatT   = vT + 4456448;              // 4,194,304
  _Float16* ipbeT   = xhatT + 4194304;           // 8,388,608
  _Float16* attnT   = ipbeT + 8388608;           // 4,194,304
  _Float16* w16qkv  = attnT + 4194304;           //   786,432
  _Float16* w16lp   = w16qkv + 786432;           //   524,288
  _Float16* w16proj = w16lp + 524288;            //   262,144
  _Float16* w16lc   = w16proj + 262144;          // 1,048,576
  _Float16* lceT    = w16lc + 1048576;           //   524,288
  _Float16* objT    = lceT + 524288;             //   524,288
  _Float16* ipp16   = objT + 524288;             // 4,194,304
  float* st = (float*)(ipp16 + 4194304);
  float* xm = st, * xr = st + 256, * om = st + 512, * orr = st + 768;

  dim3 blk(256);
  k_init<<<dim3(3072), blk, 0, stream>>>(x, obj_class, xm, xr, om, orr,
                                         qkv_w, w16qkv, lp_w, w16lp, proj_w, w16proj, lc_w, w16lc);
  k_prep<<<dim3(3328), blk, 0, stream>>>(x, xm, xr, g_qkv, b_qkv, xhatT,
                                         ipbe, ipbeT,
                                         xf_out, obj_class, obj_bbox, om, orr, g_obj, b_obj,
                                         lceT, objT);
  k_mfma_big<<<dim3(1120), blk, 0, stream>>>(w16qkv, qkv_b, xhatT,
                                             w16lp, lp_b, ipbeT,
                                             w16lc, lc_b, lceT, objT,
                                             g_lpos, b_lpos,
                                             qT, kT, vT, ipp16);
  k_ipp_fuse<<<dim3(32, 8), blk, 0, stream>>>(ipp16, g_ipos, b_ipos, qT, kT);
  k_attn_mfma<<<dim3(256), dim3(512), 0, stream>>>(qT, kT, vT, mask, attnT);
  k_mfma_proj<<<dim3(8, 4, 8), blk, 0, stream>>>(w16proj, proj_b, attnT, x, out);
}